// Round 3
// baseline (23483.836 us; speedup 1.0000x reference)
//
#include <hip/hip_runtime.h>
#include <hip/hip_bf16.h>

// ScannedRNN: 2-cell LayerNorm-GRU scan. T=512, B=128, H=512.
// Persistent 64-WG kernel. NO grid barriers: point-to-point dataflow via
// per-producer epoch flags in MALL (agent-scope relaxed atomics, sc1 path).
// Per step t (parity p=t&1):
//   G1 ins-half (indep) -> wait h2 flags(t) -> G1 h-half -> store pre0[p],
//   flag0=t+1 -> EW0 (wait 4 col-producers) -> h1[p], flag1 -> G2 (wait 2
//   row-producers) -> pre1[p], flag2 -> EW1 (wait 4) -> h2[p]+ys, flag3.
// Step-parity double buffers make <=1-step run-ahead safe (WAR-free).

#define TT 512
#define BB 128
#define HH 512
#define NWG 64
#define CPW 32            // weight columns per WG per cell
#define FLAG_WORD 32768   // resets-dtype flag (word index in cnt region)

typedef __attribute__((ext_vector_type(8))) short short8;
typedef __attribute__((ext_vector_type(4))) float f32x4;
typedef unsigned long long u64;

__device__ __forceinline__ short f2bf(float f) {
  unsigned u = __float_as_uint(f);
  unsigned r = (u + 0x7fffu + ((u >> 16) & 1u)) >> 16;
  return (short)r;
}
__device__ __forceinline__ float sigf(float x) { return 1.f / (1.f + __expf(-x)); }

// ---- MALL-coherent access (agent-scope relaxed -> sc1, bypasses per-XCD L2) ----
__device__ __forceinline__ void stf(float* p, float v) {
  __hip_atomic_store(p, v, __ATOMIC_RELAXED, __HIP_MEMORY_SCOPE_AGENT);
}
__device__ __forceinline__ void st64(void* p, u64 v) {
  __hip_atomic_store((u64*)p, v, __ATOMIC_RELAXED, __HIP_MEMORY_SCOPE_AGENT);
}
__device__ __forceinline__ u64 ld64(const void* p) {
  return __hip_atomic_load((const u64*)p, __ATOMIC_RELAXED, __HIP_MEMORY_SCOPE_AGENT);
}
__device__ __forceinline__ short8 ldbf8(const short* p) {
  u64 a = ld64(p), b = ld64(p + 4);
  short8 r;
  r[0] = (short)a; r[1] = (short)(a >> 16); r[2] = (short)(a >> 32); r[3] = (short)(a >> 48);
  r[4] = (short)b; r[5] = (short)(b >> 16); r[6] = (short)(b >> 32); r[7] = (short)(b >> 48);
  return r;
}
__device__ __forceinline__ void ld2f(const float* p, float& x, float& y) {
  u64 v = ld64(p);
  x = __uint_as_float((unsigned)v);
  y = __uint_as_float((unsigned)(v >> 32));
}
__device__ __forceinline__ u64 pk4(float a, float b, float c, float d) {
  return (u64)(unsigned short)f2bf(a) | ((u64)(unsigned short)f2bf(b) << 16)
       | ((u64)(unsigned short)f2bf(c) << 32) | ((u64)(unsigned short)f2bf(d) << 48);
}

// ---- epoch flags: flags[ph*64 + producer], monotonically increasing ----
__device__ __forceinline__ unsigned ldflag(const unsigned* p) {
  return __hip_atomic_load(p, __ATOMIC_RELAXED, __HIP_MEMORY_SCOPE_AGENT);
}
__device__ __forceinline__ void stflag(unsigned* p, unsigned v) {
  __hip_atomic_store(p, v, __ATOMIC_RELAXED, __HIP_MEMORY_SCOPE_AGENT);
}
__device__ __forceinline__ void wait2(const unsigned* f, int a, int b, unsigned tgt) {
  while (ldflag(f + a) < tgt || ldflag(f + b) < tgt) __builtin_amdgcn_s_sleep(1);
  asm volatile("" ::: "memory");
}
__device__ __forceinline__ void wait4(const unsigned* f, int a, unsigned tgt) {
  while (ldflag(f + a) < tgt || ldflag(f + a + 16) < tgt ||
         ldflag(f + a + 32) < tgt || ldflag(f + a + 48) < tgt)
    __builtin_amdgcn_s_sleep(1);
  asm volatile("" ::: "memory");
}

// ---------------- pack: weights f32 -> bf16, combined/augmented layouts ----------------
__global__ void pack_kernel(const float* __restrict__ Wi, const float* __restrict__ Wh_rz,
                            const float* __restrict__ Wh_n, const float* __restrict__ h0,
                            const void* __restrict__ resets,
                            short* __restrict__ W0p, short* __restrict__ W1p,
                            short* __restrict__ h2bf, unsigned* __restrict__ cnt) {
  int gid = blockIdx.x * 256 + threadIdx.x;
  if (gid == 0) {
    const unsigned char* rb = (const unsigned char*)resets;
    unsigned intmode = 1u;
    for (int i = 1; i < 4096; ++i) {
      if ((i & 3) && rb[i]) { intmode = 0u; break; }
    }
    cnt[FLAG_WORD] = intmode;
  }
  const int n0 = 2048 * 128;
  const int n1 = 2048 * 64;
  const int n2 = (BB * HH) / 8;
  if (gid < n0) {
    int col = gid & 2047, kb = (gid >> 11) * 8;
    int reg = col >> 9, j = col & 511;
    short8 o;
#pragma unroll
    for (int i = 0; i < 8; ++i) {
      int k = kb + i; float v;
      if (reg == 0)      v = (k < 512) ? Wi[(size_t)k * 1536 + j]        : Wh_rz[(size_t)(k - 512) * 1024 + j];
      else if (reg == 1) v = (k < 512) ? Wi[(size_t)k * 1536 + 512 + j]  : Wh_rz[(size_t)(k - 512) * 1024 + 512 + j];
      else if (reg == 2) v = (k < 512) ? Wi[(size_t)k * 1536 + 1024 + j] : 0.f;
      else               v = (k < 512) ? 0.f                             : Wh_n[(size_t)(k - 512) * 512 + j];
      o[i] = f2bf(v);
    }
    *(short8*)&W0p[(size_t)col * 1024 + kb] = o;
  } else if (gid < n0 + n1) {
    int g = gid - n0;
    int col = g & 2047, kb = (g >> 11) * 8;
    int reg = col >> 9, j = col & 511;
    const float* Wi1  = Wi + (size_t)512 * 1536;
    const float* Wrz1 = Wh_rz + (size_t)512 * 1024;
    const float* Wn1  = Wh_n + (size_t)512 * 512;
    short8 o;
#pragma unroll
    for (int i = 0; i < 8; ++i) {
      int k = kb + i; float v;
      if (reg == 0)      v = Wi1[(size_t)k * 1536 + j] + Wrz1[(size_t)k * 1024 + j];
      else if (reg == 1) v = Wi1[(size_t)k * 1536 + 512 + j] + Wrz1[(size_t)k * 1024 + 512 + j];
      else if (reg == 2) v = Wi1[(size_t)k * 1536 + 1024 + j];
      else               v = Wn1[(size_t)k * 512 + j];
      o[i] = f2bf(v);
    }
    *(short8*)&W1p[(size_t)col * 512 + kb] = o;
  } else if (gid < n0 + n1 + n2) {
    int g = gid - n0 - n1;
    short8 o;
#pragma unroll
    for (int i = 0; i < 8; ++i) o[i] = f2bf(h0[(size_t)g * 8 + i]);
    *(short8*)&h2bf[(size_t)g * 8] = o;                 // parity 0
    *(short8*)&h2bf[(size_t)BB * HH + (size_t)g * 8] = o; // parity 1 (used at t=0)
  }
}

// ---------------- persistent scan kernel ----------------
__global__ __launch_bounds__(256, 1) void rnn_scan(
    const float* __restrict__ ins, const void* __restrict__ resets,
    const float* __restrict__ h0, const float* __restrict__ bi,
    const float* __restrict__ bh_n, const float* __restrict__ ln_s,
    const float* __restrict__ ln_b,
    const short* __restrict__ W0p, const short* __restrict__ W1p,
    short* __restrict__ h1bf, short* __restrict__ h2bf,
    float* __restrict__ pre0, float* __restrict__ pre1,
    unsigned* __restrict__ cnt, float* __restrict__ out) {
  __shared__ short ldsW0[CPW * 1024];  // 64KB, [col][k] swizzled
  __shared__ short ldsW1[CPW * 512];   // 32KB
  __shared__ float h1loc[2][HH];       // this WG's 2 rows, f32 state (thread-private elems)
  __shared__ float h2loc[2][HH];
  __shared__ float red[4][4];

  const int tid = threadIdx.x;
  const int wg  = blockIdx.x;
  const int wv  = tid >> 6;
  const int l   = tid & 63;
  const int c16 = l & 15;
  const int kc  = l >> 4;
  const int rmode = (int)cnt[FLAG_WORD];
  const unsigned char* r8 = (const unsigned char*)resets;
  const int* r32 = (const int*)resets;
  float* ys = out + BB * HH;

  for (int i = tid; i < CPW * 1024 / 8; i += 256) {
    int s = i * 8; int c = s >> 10; int sw = s ^ ((c & 7) << 3);
    *(short8*)&ldsW0[sw] = *(const short8*)&W0p[(size_t)(wg * CPW + c) * 1024 + (s & 1023)];
  }
  for (int i = tid; i < CPW * 512 / 8; i += 256) {
    int s = i * 8; int c = s >> 9; int sw = s ^ ((c & 7) << 3);
    *(short8*)&ldsW1[sw] = *(const short8*)&W1p[(size_t)(wg * CPW + c) * 512 + (s & 511)];
  }
  for (int i = tid; i < 2 * HH; i += 256)
    h2loc[i >> 9][i & 511] = h0[(size_t)(wg * 2 + (i >> 9)) * HH + (i & 511)];
  __syncthreads();

  // geometry
  const int mt0 = wv * 2, mt1 = wv * 2 + 1;
  const int ar0 = mt0 * 16 + c16, ar1 = mt1 * 16 + c16; // A rows this lane loads
  const int hp0 = ar0 >> 1, hp1 = ar1 >> 1;             // their producer WGs
  const int rloc = tid >> 7;
  const int row  = wg * 2 + rloc;                       // EW row owned
  const int j0   = (tid & 127) * 4;                     // EW column quad
  const int ewp  = (tid & 127) >> 3;                    // EW flag producer base
  const int kof  = kc * 8;
  const int cg   = wg * CPW + c16;

  // hoisted EW constants (step-invariant)
  const float4 c0_br = *(const float4*)&bi[j0];
  const float4 c0_bz = *(const float4*)&bi[512 + j0];
  const float4 c0_bn = *(const float4*)&bi[1024 + j0];
  const float4 c0_bh = *(const float4*)&bh_n[j0];
  const float4 c0_sr = *(const float4*)&ln_s[j0],       c0_or = *(const float4*)&ln_b[j0];
  const float4 c0_sz = *(const float4*)&ln_s[512 + j0], c0_oz = *(const float4*)&ln_b[512 + j0];
  const float4 c1_br = *(const float4*)&bi[1536 + j0];
  const float4 c1_bz = *(const float4*)&bi[2048 + j0];
  const float4 c1_bn = *(const float4*)&bi[2560 + j0];
  const float4 c1_bh = *(const float4*)&bh_n[512 + j0];
  const float4 c1_sr = *(const float4*)&ln_s[1024 + j0], c1_or = *(const float4*)&ln_b[1024 + j0];
  const float4 c1_sz = *(const float4*)&ln_s[1536 + j0], c1_oz = *(const float4*)&ln_b[1536 + j0];

  for (int t = 0; t < TT; ++t) {
    const int p = t & 1;
    float* pre0p = pre0 + (size_t)p * BB * 2048;
    float* pre1p = pre1 + (size_t)p * BB * 2048;
    short* h1p   = h1bf + (size_t)p * BB * HH;

    // ---- G1: pre0 = [ins[t] | h_masked] @ W0p  (K=1024) ----
    {
      const float* insT = ins + (size_t)t * BB * HH;
      const bool rs0 = rmode ? (r32[t * BB + ar0] != 0) : (r8[t * BB + ar0] != 0);
      const bool rs1 = rmode ? (r32[t * BB + ar1] != 0) : (r8[t * BB + ar1] != 0);
      f32x4 a00 = {0,0,0,0}, a01 = {0,0,0,0}, a10 = {0,0,0,0}, a11 = {0,0,0,0};
      // ins half first: no cross-WG dependency -> overlaps producers' flag propagation
#pragma unroll 4
      for (int kt = 0; kt < 16; ++kt) {
        int k = kt * 32 + kof;
        const float* p0 = insT + (size_t)ar0 * HH + k;
        const float* p1 = insT + (size_t)ar1 * HH + k;
        float4 u0 = *(const float4*)p0, u1 = *(const float4*)(p0 + 4);
        float4 w0 = *(const float4*)p1, w1 = *(const float4*)(p1 + 4);
        short8 va, vb;
        va[0] = f2bf(u0.x); va[1] = f2bf(u0.y); va[2] = f2bf(u0.z); va[3] = f2bf(u0.w);
        va[4] = f2bf(u1.x); va[5] = f2bf(u1.y); va[6] = f2bf(u1.z); va[7] = f2bf(u1.w);
        vb[0] = f2bf(w0.x); vb[1] = f2bf(w0.y); vb[2] = f2bf(w0.z); vb[3] = f2bf(w0.w);
        vb[4] = f2bf(w1.x); vb[5] = f2bf(w1.y); vb[6] = f2bf(w1.z); vb[7] = f2bf(w1.w);
        int s0 = (c16 << 10) + kt * 32 + kof;        s0 ^= (c16 & 7) << 3;
        int s1 = ((16 + c16) << 10) + kt * 32 + kof; s1 ^= (c16 & 7) << 3;
        short8 b0 = *(const short8*)&ldsW0[s0];
        short8 b1 = *(const short8*)&ldsW0[s1];
        a00 = __builtin_amdgcn_mfma_f32_16x16x32_bf16(va, b0, a00, 0, 0, 0);
        a01 = __builtin_amdgcn_mfma_f32_16x16x32_bf16(va, b1, a01, 0, 0, 0);
        a10 = __builtin_amdgcn_mfma_f32_16x16x32_bf16(vb, b0, a10, 0, 0, 0);
        a11 = __builtin_amdgcn_mfma_f32_16x16x32_bf16(vb, b1, a11, 0, 0, 0);
      }
      if (t > 0) wait2(cnt + 3 * 64, hp0, hp1, (unsigned)t);  // h2(t-1) ready
      const short* hprev = h2bf + (size_t)(p ^ 1) * BB * HH;
#pragma unroll 4
      for (int kt = 16; kt < 32; ++kt) {
        int gk = (kt - 16) * 32 + kof;
        short8 va = {}, vb = {};
        if (!rs0) va = ldbf8(&hprev[(size_t)ar0 * HH + gk]);
        if (!rs1) vb = ldbf8(&hprev[(size_t)ar1 * HH + gk]);
        int s0 = (c16 << 10) + kt * 32 + kof;        s0 ^= (c16 & 7) << 3;
        int s1 = ((16 + c16) << 10) + kt * 32 + kof; s1 ^= (c16 & 7) << 3;
        short8 b0 = *(const short8*)&ldsW0[s0];
        short8 b1 = *(const short8*)&ldsW0[s1];
        a00 = __builtin_amdgcn_mfma_f32_16x16x32_bf16(va, b0, a00, 0, 0, 0);
        a01 = __builtin_amdgcn_mfma_f32_16x16x32_bf16(va, b1, a01, 0, 0, 0);
        a10 = __builtin_amdgcn_mfma_f32_16x16x32_bf16(vb, b0, a10, 0, 0, 0);
        a11 = __builtin_amdgcn_mfma_f32_16x16x32_bf16(vb, b1, a11, 0, 0, 0);
      }
#pragma unroll
      for (int r = 0; r < 4; ++r) {
        int row0 = mt0 * 16 + kc * 4 + r, row1 = mt1 * 16 + kc * 4 + r;
        stf(&pre0p[(size_t)row0 * 2048 + cg],      a00[r]);
        stf(&pre0p[(size_t)row0 * 2048 + cg + 16], a01[r]);
        stf(&pre0p[(size_t)row1 * 2048 + cg],      a10[r]);
        stf(&pre0p[(size_t)row1 * 2048 + cg + 16], a11[r]);
      }
    }
    __syncthreads();                       // drains all sc1 stores (vmcnt)
    if (tid == 0) stflag(&cnt[0 * 64 + wg], t + 1);

    // ---- EW0 ----
    {
      wait4(cnt + 0 * 64, ewp, t + 1);
      const float* prow = pre0p + (size_t)row * 2048;
      float pr[4], pz[4], xn[4], hn[4];
      ld2f(prow + j0, pr[0], pr[1]);          ld2f(prow + j0 + 2, pr[2], pr[3]);
      ld2f(prow + 512 + j0, pz[0], pz[1]);    ld2f(prow + 512 + j0 + 2, pz[2], pz[3]);
      ld2f(prow + 1024 + j0, xn[0], xn[1]);   ld2f(prow + 1024 + j0 + 2, xn[2], xn[3]);
      ld2f(prow + 1536 + j0, hn[0], hn[1]);   ld2f(prow + 1536 + j0 + 2, hn[2], hn[3]);
      float sr = 0, sr2 = 0, sz = 0, sz2 = 0;
#pragma unroll
      for (int q = 0; q < 4; ++q) {
        pr[q] += ((const float*)&c0_br)[q];
        pz[q] += ((const float*)&c0_bz)[q];
        sr += pr[q]; sr2 += pr[q] * pr[q];
        sz += pz[q]; sz2 += pz[q] * pz[q];
      }
#pragma unroll
      for (int off = 32; off >= 1; off >>= 1) {
        sr += __shfl_xor(sr, off); sr2 += __shfl_xor(sr2, off);
        sz += __shfl_xor(sz, off); sz2 += __shfl_xor(sz2, off);
      }
      if (l == 0) { red[wv][0] = sr; red[wv][1] = sr2; red[wv][2] = sz; red[wv][3] = sz2; }
      __syncthreads();
      int w0 = rloc * 2;
      float Sr = red[w0][0] + red[w0 + 1][0], Sr2 = red[w0][1] + red[w0 + 1][1];
      float Sz = red[w0][2] + red[w0 + 1][2], Sz2 = red[w0][3] + red[w0 + 1][3];
      float mr = Sr * (1.f / 512.f), vr = Sr2 * (1.f / 512.f) - mr * mr;
      float mz = Sz * (1.f / 512.f), vz = Sz2 * (1.f / 512.f) - mz * mz;
      float ir = rsqrtf(vr + 1e-6f), iz = rsqrtf(vz + 1e-6f);
      const bool rst = rmode ? (r32[t * BB + row] != 0) : (r8[t * BB + row] != 0);
      float4 hold = *(const float4*)&h2loc[rloc][j0];
      float4 h1q;
#pragma unroll
      for (int q = 0; q < 4; ++q) {
        float rg = sigf((pr[q] - mr) * ir * ((const float*)&c0_sr)[q] + ((const float*)&c0_or)[q]);
        float zg = sigf((pz[q] - mz) * iz * ((const float*)&c0_sz)[q] + ((const float*)&c0_oz)[q]);
        float nn = tanhf(xn[q] + ((const float*)&c0_bn)[q] + rg * (hn[q] + ((const float*)&c0_bh)[q]));
        float hp = rst ? 0.f : ((const float*)&hold)[q];
        ((float*)&h1q)[q] = (1.f - zg) * nn + zg * hp;
      }
      *(float4*)&h1loc[rloc][j0] = h1q;
      st64(&h1p[(size_t)row * HH + j0], pk4(h1q.x, h1q.y, h1q.z, h1q.w));
    }
    __syncthreads();
    if (tid == 0) stflag(&cnt[1 * 64 + wg], t + 1);

    // ---- G2: pre1 = h1 @ W1p  (K=512) ----
    {
      wait2(cnt + 1 * 64, hp0, hp1, (unsigned)(t + 1));
      f32x4 a00 = {0,0,0,0}, a01 = {0,0,0,0}, a10 = {0,0,0,0}, a11 = {0,0,0,0};
#pragma unroll 4
      for (int kt = 0; kt < 16; ++kt) {
        int k = kt * 32 + kof;
        short8 va = ldbf8(&h1p[(size_t)ar0 * HH + k]);
        short8 vb = ldbf8(&h1p[(size_t)ar1 * HH + k]);
        int s0 = (c16 << 9) + kt * 32 + kof;        s0 ^= (c16 & 7) << 3;
        int s1 = ((16 + c16) << 9) + kt * 32 + kof; s1 ^= (c16 & 7) << 3;
        short8 b0 = *(const short8*)&ldsW1[s0];
        short8 b1 = *(const short8*)&ldsW1[s1];
        a00 = __builtin_amdgcn_mfma_f32_16x16x32_bf16(va, b0, a00, 0, 0, 0);
        a01 = __builtin_amdgcn_mfma_f32_16x16x32_bf16(va, b1, a01, 0, 0, 0);
        a10 = __builtin_amdgcn_mfma_f32_16x16x32_bf16(vb, b0, a10, 0, 0, 0);
        a11 = __builtin_amdgcn_mfma_f32_16x16x32_bf16(vb, b1, a11, 0, 0, 0);
      }
#pragma unroll
      for (int r = 0; r < 4; ++r) {
        int row0 = mt0 * 16 + kc * 4 + r, row1 = mt1 * 16 + kc * 4 + r;
        stf(&pre1p[(size_t)row0 * 2048 + cg],      a00[r]);
        stf(&pre1p[(size_t)row0 * 2048 + cg + 16], a01[r]);
        stf(&pre1p[(size_t)row1 * 2048 + cg],      a10[r]);
        stf(&pre1p[(size_t)row1 * 2048 + cg + 16], a11[r]);
      }
    }
    __syncthreads();
    if (tid == 0) stflag(&cnt[2 * 64 + wg], t + 1);

    // ---- EW1 (+ys, out) ----
    {
      wait4(cnt + 2 * 64, ewp, t + 1);
      const float* prow = pre1p + (size_t)row * 2048;
      float pr[4], pz[4], xn[4], hn[4];
      ld2f(prow + j0, pr[0], pr[1]);          ld2f(prow + j0 + 2, pr[2], pr[3]);
      ld2f(prow + 512 + j0, pz[0], pz[1]);    ld2f(prow + 512 + j0 + 2, pz[2], pz[3]);
      ld2f(prow + 1024 + j0, xn[0], xn[1]);   ld2f(prow + 1024 + j0 + 2, xn[2], xn[3]);
      ld2f(prow + 1536 + j0, hn[0], hn[1]);   ld2f(prow + 1536 + j0 + 2, hn[2], hn[3]);
      float sr = 0, sr2 = 0, sz = 0, sz2 = 0;
#pragma unroll
      for (int q = 0; q < 4; ++q) {
        pr[q] += ((const float*)&c1_br)[q];
        pz[q] += ((const float*)&c1_bz)[q];
        sr += pr[q]; sr2 += pr[q] * pr[q];
        sz += pz[q]; sz2 += pz[q] * pz[q];
      }
#pragma unroll
      for (int off = 32; off >= 1; off >>= 1) {
        sr += __shfl_xor(sr, off); sr2 += __shfl_xor(sr2, off);
        sz += __shfl_xor(sz, off); sz2 += __shfl_xor(sz2, off);
      }
      if (l == 0) { red[wv][0] = sr; red[wv][1] = sr2; red[wv][2] = sz; red[wv][3] = sz2; }
      __syncthreads();
      int w0 = rloc * 2;
      float Sr = red[w0][0] + red[w0 + 1][0], Sr2 = red[w0][1] + red[w0 + 1][1];
      float Sz = red[w0][2] + red[w0 + 1][2], Sz2 = red[w0][3] + red[w0 + 1][3];
      float mr = Sr * (1.f / 512.f), vr = Sr2 * (1.f / 512.f) - mr * mr;
      float mz = Sz * (1.f / 512.f), vz = Sz2 * (1.f / 512.f) - mz * mz;
      float ir = rsqrtf(vr + 1e-6f), iz = rsqrtf(vz + 1e-6f);
      float4 hold = *(const float4*)&h1loc[rloc][j0];
      float4 h2q;
#pragma unroll
      for (int q = 0; q < 4; ++q) {
        float rg = sigf((pr[q] - mr) * ir * ((const float*)&c1_sr)[q] + ((const float*)&c1_or)[q]);
        float zg = sigf((pz[q] - mz) * iz * ((const float*)&c1_sz)[q] + ((const float*)&c1_oz)[q]);
        float nn = tanhf(xn[q] + ((const float*)&c1_bn)[q] + rg * (hn[q] + ((const float*)&c1_bh)[q]));
        float hp = ((const float*)&hold)[q];
        ((float*)&h2q)[q] = (1.f - zg) * nn + zg * hp;
      }
      *(float4*)&h2loc[rloc][j0] = h2q;
      st64(&h2bf[(size_t)p * BB * HH + (size_t)row * HH + j0], pk4(h2q.x, h2q.y, h2q.z, h2q.w));
      *(float4*)&ys[(size_t)t * BB * HH + (size_t)row * HH + j0] = h2q;
      if (t == TT - 1) *(float4*)&out[(size_t)row * HH + j0] = h2q;
    }
    __syncthreads();
    if (tid == 0) stflag(&cnt[3 * 64 + wg], t + 1);
  }
}

extern "C" void kernel_launch(void* const* d_in, const int* in_sizes, int n_in,
                              void* d_out, int out_size, void* d_ws, size_t ws_size,
                              hipStream_t stream) {
  const float* ins   = (const float*)d_in[0];
  const void*  rstp  = d_in[1];
  const float* h0    = (const float*)d_in[2];
  const float* Wi    = (const float*)d_in[3];
  const float* bi    = (const float*)d_in[4];
  const float* Wh_rz = (const float*)d_in[5];
  const float* Wh_n  = (const float*)d_in[6];
  const float* bh_n  = (const float*)d_in[7];
  const float* ln_s  = (const float*)d_in[8];
  const float* ln_b  = (const float*)d_in[9];
  (void)in_sizes; (void)n_in; (void)out_size; (void)ws_size;

  char* ws = (char*)d_ws;
  unsigned* cnt = (unsigned*)ws;                  // flags (1KB) + rmode flag @128KB
  size_t off = 144 * 1024;
  short* W0p  = (short*)(ws + off); off += (size_t)2048 * 1024 * 2;
  short* W1p  = (short*)(ws + off); off += (size_t)2048 * 512 * 2;
  short* h1bf = (short*)(ws + off); off += (size_t)2 * BB * HH * 2;   // x2 parity
  short* h2bf = (short*)(ws + off); off += (size_t)2 * BB * HH * 2;
  float* pre0 = (float*)(ws + off); off += (size_t)2 * BB * 2048 * 4;
  float* pre1 = (float*)(ws + off); off += (size_t)2 * BB * 2048 * 4;
  // total ws use ~10.7 MB

  hipMemsetAsync(cnt, 0, (FLAG_WORD + 1) * sizeof(unsigned), stream);
  pack_kernel<<<1568, 256, 0, stream>>>(Wi, Wh_rz, Wh_n, h0, rstp, W0p, W1p, h2bf, cnt);
  rnn_scan<<<NWG, 256, 0, stream>>>(ins, rstp, h0, bi, bh_n, ln_s, ln_b,
                                    W0p, W1p, h1bf, h2bf, pre0, pre1, cnt, (float*)d_out);
}

// Round 4
// 13985.297 us; speedup vs baseline: 1.6792x; 1.6792x over previous
//
#include <hip/hip_runtime.h>
#include <hip/hip_bf16.h>

// ScannedRNN: 2-cell LayerNorm-GRU scan. T=512, B=128, H=512.
// Graph-of-kernels design: 4 small kernels per step enqueued on `stream`
// (the harness graph-captures them -> 2049-node graph). Kernel boundaries
// provide cross-XCD coherence, so no atomics/flags/sc1 anywhere.
//   G1:  pre0[128][2048] = [ins[t] | h2_masked] @ W0p   (K=1024, bf16 MFMA)
//   EW0: LN+gates cell0 -> h1 (bf16 + f32)
//   G2:  pre1[128][2048] = h1 @ W1p                     (K=512)
//   EW1: LN+gates cell1 -> h2 (bf16 + f32), ys[t], out at t=T-1

#define TT 512
#define BB 128
#define HH 512
#define FLAG_WORD 32768   // resets-dtype flag (word index in cnt region)

typedef __attribute__((ext_vector_type(8))) short short8;
typedef __attribute__((ext_vector_type(4))) float f32x4;
typedef unsigned long long u64;

__device__ __forceinline__ short f2bf(float f) {
  unsigned u = __float_as_uint(f);
  unsigned r = (u + 0x7fffu + ((u >> 16) & 1u)) >> 16;
  return (short)r;
}
__device__ __forceinline__ float sigf(float x) { return 1.f / (1.f + __expf(-x)); }
__device__ __forceinline__ u64 pk4(float a, float b, float c, float d) {
  return (u64)(unsigned short)f2bf(a) | ((u64)(unsigned short)f2bf(b) << 16)
       | ((u64)(unsigned short)f2bf(c) << 32) | ((u64)(unsigned short)f2bf(d) << 48);
}

// ---------------- pack: weights f32 -> bf16, combined/augmented layouts ----------------
// W0p [2048 cols][1024 k]: cols 0..511 r, 512..1023 z, 1024..1535 xn (ins-half
// only), 1536..2047 hn (h-half only); k<512 = ins (Wi[0]), k>=512 = h.
// W1p [2048 cols][512 k]: r,z = (Wi1+Whrz1), xn = Wi1_n, hn = Whn1.
__global__ void pack_kernel(const float* __restrict__ Wi, const float* __restrict__ Wh_rz,
                            const float* __restrict__ Wh_n, const float* __restrict__ h0,
                            const void* __restrict__ resets,
                            short* __restrict__ W0p, short* __restrict__ W1p,
                            short* __restrict__ h2bf, float* __restrict__ h2f32,
                            unsigned* __restrict__ cnt) {
  int gid = blockIdx.x * 256 + threadIdx.x;
  if (gid == 0) {
    // detect resets dtype: int32 (bytes i%4!=0 all zero over a window) vs bool
    const unsigned char* rb = (const unsigned char*)resets;
    unsigned intmode = 1u;
    for (int i = 1; i < 4096; ++i) {
      if ((i & 3) && rb[i]) { intmode = 0u; break; }
    }
    cnt[FLAG_WORD] = intmode;
  }
  const int n0 = 2048 * 128;
  const int n1 = 2048 * 64;
  const int n2 = (BB * HH) / 8;
  if (gid < n0) {
    int col = gid & 2047, kb = (gid >> 11) * 8;
    int reg = col >> 9, j = col & 511;
    short8 o;
#pragma unroll
    for (int i = 0; i < 8; ++i) {
      int k = kb + i; float v;
      if (reg == 0)      v = (k < 512) ? Wi[(size_t)k * 1536 + j]        : Wh_rz[(size_t)(k - 512) * 1024 + j];
      else if (reg == 1) v = (k < 512) ? Wi[(size_t)k * 1536 + 512 + j]  : Wh_rz[(size_t)(k - 512) * 1024 + 512 + j];
      else if (reg == 2) v = (k < 512) ? Wi[(size_t)k * 1536 + 1024 + j] : 0.f;
      else               v = (k < 512) ? 0.f                             : Wh_n[(size_t)(k - 512) * 512 + j];
      o[i] = f2bf(v);
    }
    *(short8*)&W0p[(size_t)col * 1024 + kb] = o;
  } else if (gid < n0 + n1) {
    int g = gid - n0;
    int col = g & 2047, kb = (g >> 11) * 8;
    int reg = col >> 9, j = col & 511;
    const float* Wi1  = Wi + (size_t)512 * 1536;
    const float* Wrz1 = Wh_rz + (size_t)512 * 1024;
    const float* Wn1  = Wh_n + (size_t)512 * 512;
    short8 o;
#pragma unroll
    for (int i = 0; i < 8; ++i) {
      int k = kb + i; float v;
      if (reg == 0)      v = Wi1[(size_t)k * 1536 + j] + Wrz1[(size_t)k * 1024 + j];
      else if (reg == 1) v = Wi1[(size_t)k * 1536 + 512 + j] + Wrz1[(size_t)k * 1024 + 512 + j];
      else if (reg == 2) v = Wi1[(size_t)k * 1536 + 1024 + j];
      else               v = Wn1[(size_t)k * 512 + j];
      o[i] = f2bf(v);
    }
    *(short8*)&W1p[(size_t)col * 512 + kb] = o;
  } else if (gid < n0 + n1 + n2) {
    int g = gid - n0 - n1;
    short8 o;
    float4 f0, f1;
#pragma unroll
    for (int i = 0; i < 8; ++i) {
      float v = h0[(size_t)g * 8 + i];
      o[i] = f2bf(v);
      if (i < 4) ((float*)&f0)[i] = v; else ((float*)&f1)[i - 4] = v;
    }
    *(short8*)&h2bf[(size_t)g * 8] = o;
    *(float4*)&h2f32[(size_t)g * 8] = f0;
    *(float4*)&h2f32[(size_t)g * 8 + 4] = f1;
  }
}

// ---------------- G1: pre0 = [ins[t] | h2_masked] @ W0p, 64 WGs x 512 thr ----------------
__global__ __launch_bounds__(512, 1) void g1_kernel(
    int t, const float* __restrict__ ins, const void* __restrict__ resets,
    const unsigned* __restrict__ cnt, const short* __restrict__ W0p,
    const short* __restrict__ h2bf, float* __restrict__ pre0) {
  __shared__ short ldsW0[32 * 1024];  // 64KB, [col][k] xor-swizzled
  const int tid = threadIdx.x, wg = blockIdx.x;
  for (int i = tid; i < 4096; i += 512) {
    int s = i * 8; int c = s >> 10; int sw = s ^ ((c & 7) << 3);
    *(short8*)&ldsW0[sw] = *(const short8*)&W0p[(size_t)(wg * 32 + c) * 1024 + (s & 1023)];
  }
  __syncthreads();
  const int l = tid & 63, c16 = l & 15, kc = l >> 4, wv = tid >> 6;
  const int ar = wv * 16 + c16;       // A row this lane loads
  const int kof = kc * 8;
  const int rmode = (int)cnt[FLAG_WORD];
  const bool rs = rmode ? (((const int*)resets)[t * BB + ar] != 0)
                        : (((const unsigned char*)resets)[t * BB + ar] != 0);
  const float* insT = ins + (size_t)t * BB * HH;
  f32x4 a0 = {0, 0, 0, 0}, a1 = {0, 0, 0, 0};
#pragma unroll 4
  for (int kt = 0; kt < 16; ++kt) {   // ins half (k < 512), f32 -> bf16
    int k = kt * 32 + kof;
    const float* p0 = insT + (size_t)ar * HH + k;
    float4 u0 = *(const float4*)p0, u1 = *(const float4*)(p0 + 4);
    short8 va;
    va[0] = f2bf(u0.x); va[1] = f2bf(u0.y); va[2] = f2bf(u0.z); va[3] = f2bf(u0.w);
    va[4] = f2bf(u1.x); va[5] = f2bf(u1.y); va[6] = f2bf(u1.z); va[7] = f2bf(u1.w);
    int s0 = (c16 << 10) + k;        s0 ^= (c16 & 7) << 3;
    int s1 = ((16 + c16) << 10) + k; s1 ^= (c16 & 7) << 3;
    short8 b0 = *(const short8*)&ldsW0[s0];
    short8 b1 = *(const short8*)&ldsW0[s1];
    a0 = __builtin_amdgcn_mfma_f32_16x16x32_bf16(va, b0, a0, 0, 0, 0);
    a1 = __builtin_amdgcn_mfma_f32_16x16x32_bf16(va, b1, a1, 0, 0, 0);
  }
  const short* hrow = h2bf + (size_t)ar * HH;
#pragma unroll 4
  for (int kt = 16; kt < 32; ++kt) {  // h half (k >= 512), reset-masked
    int gk = (kt - 16) * 32 + kof;
    short8 va = {};
    if (!rs) va = *(const short8*)&hrow[gk];
    int s0 = (c16 << 10) + kt * 32 + kof;        s0 ^= (c16 & 7) << 3;
    int s1 = ((16 + c16) << 10) + kt * 32 + kof; s1 ^= (c16 & 7) << 3;
    short8 b0 = *(const short8*)&ldsW0[s0];
    short8 b1 = *(const short8*)&ldsW0[s1];
    a0 = __builtin_amdgcn_mfma_f32_16x16x32_bf16(va, b0, a0, 0, 0, 0);
    a1 = __builtin_amdgcn_mfma_f32_16x16x32_bf16(va, b1, a1, 0, 0, 0);
  }
  const int cg = wg * 32 + c16;
#pragma unroll
  for (int r = 0; r < 4; ++r) {
    int row = wv * 16 + kc * 4 + r;
    pre0[(size_t)row * 2048 + cg]      = a0[r];
    pre0[(size_t)row * 2048 + cg + 16] = a1[r];
  }
}

// ---------------- G2: pre1 = h1 @ W1p (K=512), 64 WGs x 512 thr ----------------
__global__ __launch_bounds__(512, 1) void g2_kernel(
    const short* __restrict__ W1p, const short* __restrict__ h1bf,
    float* __restrict__ pre1) {
  __shared__ short ldsW1[32 * 512];   // 32KB
  const int tid = threadIdx.x, wg = blockIdx.x;
  for (int i = tid; i < 2048; i += 512) {
    int s = i * 8; int c = s >> 9; int sw = s ^ ((c & 7) << 3);
    *(short8*)&ldsW1[sw] = *(const short8*)&W1p[(size_t)(wg * 32 + c) * 512 + (s & 511)];
  }
  __syncthreads();
  const int l = tid & 63, c16 = l & 15, kc = l >> 4, wv = tid >> 6;
  const int ar = wv * 16 + c16;
  const int kof = kc * 8;
  const short* hrow = h1bf + (size_t)ar * HH;
  f32x4 a0 = {0, 0, 0, 0}, a1 = {0, 0, 0, 0};
#pragma unroll 4
  for (int kt = 0; kt < 16; ++kt) {
    int k = kt * 32 + kof;
    short8 va = *(const short8*)&hrow[k];
    int s0 = (c16 << 9) + k;        s0 ^= (c16 & 7) << 3;
    int s1 = ((16 + c16) << 9) + k; s1 ^= (c16 & 7) << 3;
    short8 b0 = *(const short8*)&ldsW1[s0];
    short8 b1 = *(const short8*)&ldsW1[s1];
    a0 = __builtin_amdgcn_mfma_f32_16x16x32_bf16(va, b0, a0, 0, 0, 0);
    a1 = __builtin_amdgcn_mfma_f32_16x16x32_bf16(va, b1, a1, 0, 0, 0);
  }
  const int cg = wg * 32 + c16;
#pragma unroll
  for (int r = 0; r < 4; ++r) {
    int row = wv * 16 + kc * 4 + r;
    pre1[(size_t)row * 2048 + cg]      = a0[r];
    pre1[(size_t)row * 2048 + cg + 16] = a1[r];
  }
}

// ---------------- EW0: LN + gates cell0 -> h1, 64 WGs x 256 thr (2 rows/WG) ----------------
__global__ __launch_bounds__(256, 1) void ew0_kernel(
    int t, const void* __restrict__ resets, const unsigned* __restrict__ cnt,
    const float* __restrict__ pre0, const float* __restrict__ bi,
    const float* __restrict__ bh_n, const float* __restrict__ ln_s,
    const float* __restrict__ ln_b, const float* __restrict__ h2f32,
    short* __restrict__ h1bf, float* __restrict__ h1f32) {
  __shared__ float red[4][4];
  const int tid = threadIdx.x, wg = blockIdx.x;
  const int wv = tid >> 6, l = tid & 63;
  const int rloc = tid >> 7;
  const int row = wg * 2 + rloc;
  const int j0 = (tid & 127) * 4;
  const int rmode = (int)cnt[FLAG_WORD];
  const float* prow = pre0 + (size_t)row * 2048;
  float4 pr = *(const float4*)&prow[j0];
  float4 pz = *(const float4*)&prow[512 + j0];
  float4 xn = *(const float4*)&prow[1024 + j0];
  float4 hn = *(const float4*)&prow[1536 + j0];
  float4 br = *(const float4*)&bi[j0];
  float4 bz = *(const float4*)&bi[512 + j0];
  float4 bn = *(const float4*)&bi[1024 + j0];
  float4 bh = *(const float4*)&bh_n[j0];
  float sr = 0, sr2 = 0, sz = 0, sz2 = 0;
#pragma unroll
  for (int q = 0; q < 4; ++q) {
    ((float*)&pr)[q] += ((const float*)&br)[q];
    ((float*)&pz)[q] += ((const float*)&bz)[q];
    float a = ((const float*)&pr)[q], b = ((const float*)&pz)[q];
    sr += a; sr2 += a * a; sz += b; sz2 += b * b;
  }
#pragma unroll
  for (int off = 32; off >= 1; off >>= 1) {
    sr += __shfl_xor(sr, off); sr2 += __shfl_xor(sr2, off);
    sz += __shfl_xor(sz, off); sz2 += __shfl_xor(sz2, off);
  }
  if (l == 0) { red[wv][0] = sr; red[wv][1] = sr2; red[wv][2] = sz; red[wv][3] = sz2; }
  __syncthreads();
  int w0 = rloc * 2;
  float Sr = red[w0][0] + red[w0 + 1][0], Sr2 = red[w0][1] + red[w0 + 1][1];
  float Sz = red[w0][2] + red[w0 + 1][2], Sz2 = red[w0][3] + red[w0 + 1][3];
  float mr = Sr * (1.f / 512.f), vr = Sr2 * (1.f / 512.f) - mr * mr;
  float mz = Sz * (1.f / 512.f), vz = Sz2 * (1.f / 512.f) - mz * mz;
  float ir = rsqrtf(vr + 1e-6f), iz = rsqrtf(vz + 1e-6f);
  const bool rst = rmode ? (((const int*)resets)[t * BB + row] != 0)
                         : (((const unsigned char*)resets)[t * BB + row] != 0);
  float4 lsr = *(const float4*)&ln_s[j0],       lbr = *(const float4*)&ln_b[j0];
  float4 lsz = *(const float4*)&ln_s[512 + j0], lbz = *(const float4*)&ln_b[512 + j0];
  float4 hold = *(const float4*)&h2f32[(size_t)row * HH + j0];
  float4 h1q;
#pragma unroll
  for (int q = 0; q < 4; ++q) {
    float rg = sigf((((const float*)&pr)[q] - mr) * ir * ((const float*)&lsr)[q] + ((const float*)&lbr)[q]);
    float zg = sigf((((const float*)&pz)[q] - mz) * iz * ((const float*)&lsz)[q] + ((const float*)&lbz)[q]);
    float nn = tanhf(((const float*)&xn)[q] + ((const float*)&bn)[q] +
                     rg * (((const float*)&hn)[q] + ((const float*)&bh)[q]));
    float hp = rst ? 0.f : ((const float*)&hold)[q];
    ((float*)&h1q)[q] = (1.f - zg) * nn + zg * hp;
  }
  *(float4*)&h1f32[(size_t)row * HH + j0] = h1q;
  *(u64*)&h1bf[(size_t)row * HH + j0] = pk4(h1q.x, h1q.y, h1q.z, h1q.w);
}

// ---------------- EW1: LN + gates cell1 -> h2, ys[t], 64 WGs x 256 thr ----------------
__global__ __launch_bounds__(256, 1) void ew1_kernel(
    int t, const float* __restrict__ pre1, const float* __restrict__ bi,
    const float* __restrict__ bh_n, const float* __restrict__ ln_s,
    const float* __restrict__ ln_b, const float* __restrict__ h1f32,
    short* __restrict__ h2bf, float* __restrict__ h2f32,
    float* __restrict__ out) {
  __shared__ float red[4][4];
  const int tid = threadIdx.x, wg = blockIdx.x;
  const int wv = tid >> 6, l = tid & 63;
  const int rloc = tid >> 7;
  const int row = wg * 2 + rloc;
  const int j0 = (tid & 127) * 4;
  const float* prow = pre1 + (size_t)row * 2048;
  const float* bi1 = bi + 1536;
  const float* ls1 = ln_s + 1024;
  const float* lb1 = ln_b + 1024;
  const float* bh1 = bh_n + 512;
  float* ys = out + BB * HH;
  float4 pr = *(const float4*)&prow[j0];
  float4 pz = *(const float4*)&prow[512 + j0];
  float4 xn = *(const float4*)&prow[1024 + j0];
  float4 hn = *(const float4*)&prow[1536 + j0];
  float4 br = *(const float4*)&bi1[j0];
  float4 bz = *(const float4*)&bi1[512 + j0];
  float4 bn = *(const float4*)&bi1[1024 + j0];
  float4 bh = *(const float4*)&bh1[j0];
  float sr = 0, sr2 = 0, sz = 0, sz2 = 0;
#pragma unroll
  for (int q = 0; q < 4; ++q) {
    ((float*)&pr)[q] += ((const float*)&br)[q];
    ((float*)&pz)[q] += ((const float*)&bz)[q];
    float a = ((const float*)&pr)[q], b = ((const float*)&pz)[q];
    sr += a; sr2 += a * a; sz += b; sz2 += b * b;
  }
#pragma unroll
  for (int off = 32; off >= 1; off >>= 1) {
    sr += __shfl_xor(sr, off); sr2 += __shfl_xor(sr2, off);
    sz += __shfl_xor(sz, off); sz2 += __shfl_xor(sz2, off);
  }
  if (l == 0) { red[wv][0] = sr; red[wv][1] = sr2; red[wv][2] = sz; red[wv][3] = sz2; }
  __syncthreads();
  int w0 = rloc * 2;
  float Sr = red[w0][0] + red[w0 + 1][0], Sr2 = red[w0][1] + red[w0 + 1][1];
  float Sz = red[w0][2] + red[w0 + 1][2], Sz2 = red[w0][3] + red[w0 + 1][3];
  float mr = Sr * (1.f / 512.f), vr = Sr2 * (1.f / 512.f) - mr * mr;
  float mz = Sz * (1.f / 512.f), vz = Sz2 * (1.f / 512.f) - mz * mz;
  float ir = rsqrtf(vr + 1e-6f), iz = rsqrtf(vz + 1e-6f);
  float4 lsr = *(const float4*)&ls1[j0],       lbr = *(const float4*)&lb1[j0];
  float4 lsz = *(const float4*)&ls1[512 + j0], lbz = *(const float4*)&lb1[512 + j0];
  float4 hold = *(const float4*)&h1f32[(size_t)row * HH + j0];
  float4 h2q;
#pragma unroll
  for (int q = 0; q < 4; ++q) {
    float rg = sigf((((const float*)&pr)[q] - mr) * ir * ((const float*)&lsr)[q] + ((const float*)&lbr)[q]);
    float zg = sigf((((const float*)&pz)[q] - mz) * iz * ((const float*)&lsz)[q] + ((const float*)&lbz)[q]);
    float nn = tanhf(((const float*)&xn)[q] + ((const float*)&bn)[q] +
                     rg * (((const float*)&hn)[q] + ((const float*)&bh)[q]));
    float hp = ((const float*)&hold)[q];
    ((float*)&h2q)[q] = (1.f - zg) * nn + zg * hp;
  }
  *(float4*)&h2f32[(size_t)row * HH + j0] = h2q;
  *(u64*)&h2bf[(size_t)row * HH + j0] = pk4(h2q.x, h2q.y, h2q.z, h2q.w);
  *(float4*)&ys[(size_t)t * BB * HH + (size_t)row * HH + j0] = h2q;
  if (t == TT - 1) *(float4*)&out[(size_t)row * HH + j0] = h2q;
}

extern "C" void kernel_launch(void* const* d_in, const int* in_sizes, int n_in,
                              void* d_out, int out_size, void* d_ws, size_t ws_size,
                              hipStream_t stream) {
  const float* ins   = (const float*)d_in[0];
  const void*  rstp  = d_in[1];
  const float* h0    = (const float*)d_in[2];
  const float* Wi    = (const float*)d_in[3];
  const float* bi    = (const float*)d_in[4];
  const float* Wh_rz = (const float*)d_in[5];
  const float* Wh_n  = (const float*)d_in[6];
  const float* bh_n  = (const float*)d_in[7];
  const float* ln_s  = (const float*)d_in[8];
  const float* ln_b  = (const float*)d_in[9];
  (void)in_sizes; (void)n_in; (void)out_size; (void)ws_size;

  char* ws = (char*)d_ws;
  unsigned* cnt = (unsigned*)ws;                  // rmode flag @ word 32768
  size_t off = 144 * 1024;
  short* W0p   = (short*)(ws + off); off += (size_t)2048 * 1024 * 2;
  short* W1p   = (short*)(ws + off); off += (size_t)2048 * 512 * 2;
  short* h1bf  = (short*)(ws + off); off += (size_t)BB * HH * 2;
  short* h2bf  = (short*)(ws + off); off += (size_t)BB * HH * 2;
  float* h1f32 = (float*)(ws + off); off += (size_t)BB * HH * 4;
  float* h2f32 = (float*)(ws + off); off += (size_t)BB * HH * 4;
  float* pre0  = (float*)(ws + off); off += (size_t)BB * 2048 * 4;
  float* pre1  = (float*)(ws + off); off += (size_t)BB * 2048 * 4;
  // total ws use ~9 MB

  pack_kernel<<<1568, 256, 0, stream>>>(Wi, Wh_rz, Wh_n, h0, rstp, W0p, W1p,
                                        h2bf, h2f32, cnt);
  float* outp = (float*)d_out;
  for (int t = 0; t < TT; ++t) {
    g1_kernel<<<64, 512, 0, stream>>>(t, ins, rstp, cnt, W0p, h2bf, pre0);
    ew0_kernel<<<64, 256, 0, stream>>>(t, rstp, cnt, pre0, bi, bh_n, ln_s, ln_b,
                                       h2f32, h1bf, h1f32);
    g2_kernel<<<64, 512, 0, stream>>>(W1p, h1bf, pre1);
    ew1_kernel<<<64, 256, 0, stream>>>(t, pre1, bi, bh_n, ln_s, ln_b,
                                       h1f32, h2bf, h2f32, outp);
  }
}

// Round 5
// 12926.839 us; speedup vs baseline: 1.8167x; 1.0819x over previous
//
#include <hip/hip_runtime.h>
#include <hip/hip_bf16.h>

// ScannedRNN: 2-cell LayerNorm-GRU scan. T=512, B=128, H=512.
// KEY IDEA: resets (~50% density) cut each batch row into independent
// segments (mean length 2, max ~20). Bucket cells by distance d from their
// segment start; process bucket d=tau in round kernel tau (24 rounds), each
// cell reading its h-input from ys[t-1,b] (round tau-1's output; kernel
// boundary = coherent). Round kernel fuses GEMM0+LN/gates0+GEMM1+LN/gates1
// per 32-row group inside ONE workgroup (LDS A, weights streamed from L2).
// 27 graph nodes total (vs 2049 in the per-step design).

#define TT 512
#define BB 128
#define HH 512
#define RCAP 24
#define FLAG_WORD 32768

typedef __attribute__((ext_vector_type(8))) short short8;
typedef __attribute__((ext_vector_type(4))) float f32x4;
typedef unsigned int u32;

__device__ __forceinline__ short f2bf(float f) {
  unsigned u = __float_as_uint(f);
  unsigned r = (u + 0x7fffu + ((u >> 16) & 1u)) >> 16;
  return (short)r;
}
__device__ __forceinline__ float bf2f(short s) {
  return __uint_as_float(((unsigned)(unsigned short)s) << 16);
}
__device__ __forceinline__ float sigf(float x) { return 1.f / (1.f + __expf(-x)); }

// ---------------- pack: weights f32 -> bf16 ----------------
// W0p [2048 cols][1024 k]: cols 0..511 r, 512..1023 z, 1024..1535 xn(ins-only),
//   1536..2047 hn(h-only); k<512 = ins (Wi[0]), k>=512 = h (Wh_rz[0]/Wh_n[0]).
// W1p [2048 cols][512 k]: r,z = Wi1+Whrz1 folded; xn = Wi1_n; hn = Whn1.
__global__ void pack_kernel(const float* __restrict__ Wi, const float* __restrict__ Wh_rz,
                            const float* __restrict__ Wh_n, const void* __restrict__ resets,
                            short* __restrict__ W0p, short* __restrict__ W1p,
                            unsigned* __restrict__ cnt) {
  int gid = blockIdx.x * 256 + threadIdx.x;
  if (gid == 0) {
    const unsigned char* rb = (const unsigned char*)resets;
    unsigned intmode = 1u;
    for (int i = 1; i < 4096; ++i) {
      if ((i & 3) && rb[i]) { intmode = 0u; break; }
    }
    cnt[FLAG_WORD] = intmode;
  }
  const int n0 = 2048 * 128;
  const int n1 = 2048 * 64;
  if (gid < n0) {
    int col = gid & 2047, kb = (gid >> 11) * 8;
    int reg = col >> 9, j = col & 511;
    short8 o;
#pragma unroll
    for (int i = 0; i < 8; ++i) {
      int k = kb + i; float v;
      if (reg == 0)      v = (k < 512) ? Wi[(size_t)k * 1536 + j]        : Wh_rz[(size_t)(k - 512) * 1024 + j];
      else if (reg == 1) v = (k < 512) ? Wi[(size_t)k * 1536 + 512 + j]  : Wh_rz[(size_t)(k - 512) * 1024 + 512 + j];
      else if (reg == 2) v = (k < 512) ? Wi[(size_t)k * 1536 + 1024 + j] : 0.f;
      else               v = (k < 512) ? 0.f                             : Wh_n[(size_t)(k - 512) * 512 + j];
      o[i] = f2bf(v);
    }
    *(short8*)&W0p[(size_t)col * 1024 + kb] = o;
  } else if (gid < n0 + n1) {
    int g = gid - n0;
    int col = g & 2047, kb = (g >> 11) * 8;
    int reg = col >> 9, j = col & 511;
    const float* Wi1  = Wi + (size_t)512 * 1536;
    const float* Wrz1 = Wh_rz + (size_t)512 * 1024;
    const float* Wn1  = Wh_n + (size_t)512 * 512;
    short8 o;
#pragma unroll
    for (int i = 0; i < 8; ++i) {
      int k = kb + i; float v;
      if (reg == 0)      v = Wi1[(size_t)k * 1536 + j] + Wrz1[(size_t)k * 1024 + j];
      else if (reg == 1) v = Wi1[(size_t)k * 1536 + 512 + j] + Wrz1[(size_t)k * 1024 + 512 + j];
      else if (reg == 2) v = Wi1[(size_t)k * 1536 + 1024 + j];
      else               v = Wn1[(size_t)k * 512 + j];
      o[i] = f2bf(v);
    }
    *(short8*)&W1p[(size_t)col * 512 + kb] = o;
  }
}

// ---------------- prep: bucket cells by d (single WG) ----------------
__global__ void prep_kernel(const void* __restrict__ resets, unsigned* __restrict__ cnt,
                            u32* __restrict__ bucket) {
  __shared__ u32 hist[RCAP + 1];
  __shared__ u32 cur[RCAP + 1];
  const int tid = threadIdx.x;
  const int rmode = (int)cnt[FLAG_WORD];
  const unsigned char* r8 = (const unsigned char*)resets;
  const int* r32 = (const int*)resets;
  if (tid <= RCAP) hist[tid] = 0;
  __syncthreads();
  if (tid < BB) {
    int d = 0;
    for (int t = 0; t < TT; ++t) {
      bool rs = rmode ? (r32[t * BB + tid] != 0) : (r8[t * BB + tid] != 0);
      d = (t == 0 || rs) ? 0 : d + 1;
      int dd = d < RCAP ? d : RCAP;
      atomicAdd(&hist[dd], 1u);
    }
  }
  __syncthreads();
  if (tid == 0) {
    u32 acc = 0;
    for (int i = 0; i <= RCAP; ++i) { u32 h = hist[i]; cur[i] = acc; cnt[i] = acc; acc += h; }
  }
  __syncthreads();
  if (tid < BB) {
    int d = 0;
    for (int t = 0; t < TT; ++t) {
      bool rs = rmode ? (r32[t * BB + tid] != 0) : (r8[t * BB + tid] != 0);
      d = (t == 0 || rs) ? 0 : d + 1;
      if (d < RCAP) {
        u32 pos = atomicAdd(&cur[d], 1u);
        bucket[pos] = ((u32)t << 7) | (u32)tid;
      }
    }
  }
}

// ---------------- round kernel: all cells at distance tau ----------------
// 256 WGs x 512 thr, 160KB LDS. Per 32-row group: stage A=[ins|h] ->
// cell0 GEMM (B streamed from L2) -> LN stats (shfl+LDS) -> gates -> combine
// -> h1 in LDS -> cell1 GEMM -> LN/gates -> combine -> ys (+out at t=511).
__global__ __launch_bounds__(512, 2) void round_kernel(
    int tau, const float* __restrict__ ins, const void* __restrict__ resets,
    const float* __restrict__ h0, const float* __restrict__ bi,
    const float* __restrict__ bh_n, const float* __restrict__ ln_s,
    const float* __restrict__ ln_b, const short* __restrict__ W0p,
    const short* __restrict__ W1p, const unsigned* __restrict__ cnt,
    const u32* __restrict__ bucket, float* __restrict__ out) {
  __shared__ short lds[81920];          // 160 KB exactly
  short* A0 = lds;                      // [32][1024] bf16, xor-swizzled rows
  short* RB = lds + 32768;              // [32][512] r-gate (later r1)
  short* ZB = lds + 49152;              // [32][512] z-gate (later z1)
  short* HB = lds + 65536;              // [32][512] hn (later hn1)
  float* st0 = (float*)lds;             // 256 f32 stats cell0 (row0 ins area, dead then)
  float* st1 = (float*)(lds + 512);     // 256 f32 stats cell1 (row0 h area, dead then)

  const int tid = threadIdx.x;
  const int l = tid & 63, wv = tid >> 6, c16 = l & 15, kc = l >> 4;
  const int gate = wv >> 1, half = wv & 1;
  const int rmode = (int)cnt[FLAG_WORD];
  const u32 boff = cnt[tau];
  const u32 M = cnt[tau + 1] - boff;
  float* ys = out + BB * HH;
  const int sw0 = (c16 & 7) << 3;       // A-row swizzle for rows c16 and 16+c16

  for (u32 g = blockIdx.x; g * 32 < M; g += gridDim.x) {
    const u32 gb = boff + g * 32;
    __syncthreads();   // protect LDS reuse across groups

    // ---- stage A0: row = [ins(t,b) | h_in] bf16, swizzled ----
    {
      const int row = tid >> 4, part = tid & 15;
      const u32 m = g * 32 + (u32)row;
      u32 e = (m < M) ? bucket[gb + row] : 0xFFFFFFFFu;
      const int t = (int)((e >> 7) & 511), b = (int)(e & 127);
      const int sw = (row & 7) << 3;
      if (e == 0xFFFFFFFFu) {
        const int k0 = part * 64;
        short8 z = {};
#pragma unroll
        for (int gg = 0; gg < 8; ++gg)
          *(short8*)&A0[row * 1024 + ((k0 + gg * 8) ^ sw)] = z;
      } else if (part < 8) {            // ins half, k in [0,512)
        const int k0 = part * 64;
        const float* src = ins + (size_t)t * (BB * HH) + (size_t)b * HH + k0;
#pragma unroll
        for (int gg = 0; gg < 8; ++gg) {
          float4 u0 = *(const float4*)(src + gg * 8);
          float4 u1 = *(const float4*)(src + gg * 8 + 4);
          short8 v;
          v[0] = f2bf(u0.x); v[1] = f2bf(u0.y); v[2] = f2bf(u0.z); v[3] = f2bf(u0.w);
          v[4] = f2bf(u1.x); v[5] = f2bf(u1.y); v[6] = f2bf(u1.z); v[7] = f2bf(u1.w);
          *(short8*)&A0[row * 1024 + ((k0 + gg * 8) ^ sw)] = v;
        }
      } else {                          // h half, k in [512,1024)
        const int k0 = (part - 8) * 64;
        const float* src = nullptr;
        bool zero = false;
        if (tau > 0) {
          src = ys + (size_t)(t - 1) * (BB * HH) + (size_t)b * HH + k0;
        } else {
          bool rs = rmode ? (((const int*)resets)[t * BB + b] != 0)
                          : (((const unsigned char*)resets)[t * BB + b] != 0);
          if (rs) zero = true; else src = h0 + (size_t)b * HH + k0;  // t==0 here
        }
#pragma unroll
        for (int gg = 0; gg < 8; ++gg) {
          short8 v = {};
          if (!zero) {
            float4 u0 = *(const float4*)(src + gg * 8);
            float4 u1 = *(const float4*)(src + gg * 8 + 4);
            v[0] = f2bf(u0.x); v[1] = f2bf(u0.y); v[2] = f2bf(u0.z); v[3] = f2bf(u0.w);
            v[4] = f2bf(u1.x); v[5] = f2bf(u1.y); v[6] = f2bf(u1.z); v[7] = f2bf(u1.w);
          }
          *(short8*)&A0[row * 1024 + ((512 + k0 + gg * 8) ^ sw)] = v;
        }
      }
    }
    __syncthreads();

    // ---- cell0 GEMM: acc[rt][ct] = A(32x1024) @ W0p-cols ----
    f32x4 acc[2][16];
#pragma unroll
    for (int rt = 0; rt < 2; ++rt)
#pragma unroll
      for (int ct = 0; ct < 16; ++ct) acc[rt][ct] = (f32x4){0.f, 0.f, 0.f, 0.f};
    for (int kb = 0; kb < 32; ++kb) {
      const int k = kb * 32 + kc * 8;
      short8 a0 = *(const short8*)&A0[c16 * 1024 + (k ^ sw0)];
      short8 a1 = *(const short8*)&A0[(16 + c16) * 1024 + (k ^ sw0)];
#pragma unroll
      for (int ct = 0; ct < 16; ++ct) {
        const int col = wv * 256 + ct * 16 + c16;
        short8 bf = *(const short8*)&W0p[(size_t)col * 1024 + k];
        acc[0][ct] = __builtin_amdgcn_mfma_f32_16x16x32_bf16(a0, bf, acc[0][ct], 0, 0, 0);
        acc[1][ct] = __builtin_amdgcn_mfma_f32_16x16x32_bf16(a1, bf, acc[1][ct], 0, 0, 0);
      }
    }
    __syncthreads();   // GEMM done; A0 row0-ins reusable for stats

    // ---- cell0: bias add + LN stats (gates r,z) ----
#pragma unroll
    for (int ct = 0; ct < 16; ++ct) {
      const int col = wv * 256 + ct * 16 + c16;
      const int j = col & 511;
      float bs = (gate == 3) ? bh_n[j] : bi[col];
#pragma unroll
      for (int rt = 0; rt < 2; ++rt)
#pragma unroll
        for (int rr = 0; rr < 4; ++rr) acc[rt][ct][rr] += bs;
    }
    if (gate < 2) {
#pragma unroll
      for (int rt = 0; rt < 2; ++rt)
#pragma unroll
        for (int rr = 0; rr < 4; ++rr) {
          float s = 0.f, q = 0.f;
#pragma unroll
          for (int ct = 0; ct < 16; ++ct) { float v = acc[rt][ct][rr]; s += v; q += v * v; }
#pragma unroll
          for (int o = 8; o >= 1; o >>= 1) { s += __shfl_xor(s, o); q += __shfl_xor(q, o); }
          if (c16 == 0) {
            const int row = rt * 16 + kc * 4 + rr;
            st0[gate * 128 + row * 4 + half * 2 + 0] = s;
            st0[gate * 128 + row * 4 + half * 2 + 1] = q;
          }
        }
    }
    __syncthreads();

    // ---- cell0 gates ----
    if (gate < 2) {
#pragma unroll
      for (int rt = 0; rt < 2; ++rt)
#pragma unroll
        for (int rr = 0; rr < 4; ++rr) {
          const int row = rt * 16 + kc * 4 + rr;
          float S = st0[gate * 128 + row * 4 + 0] + st0[gate * 128 + row * 4 + 2];
          float Q = st0[gate * 128 + row * 4 + 1] + st0[gate * 128 + row * 4 + 3];
          float m = S * (1.f / 512.f);
          float vv = Q * (1.f / 512.f) - m * m;
          float ir = rsqrtf(vv + 1e-6f);
#pragma unroll
          for (int ct = 0; ct < 16; ++ct) {
            const int col = wv * 256 + ct * 16 + c16;
            const int j = col & 511;
            float gv = sigf((acc[rt][ct][rr] - m) * ir * ln_s[gate * 512 + j] + ln_b[gate * 512 + j]);
            ((gate == 0) ? RB : ZB)[row * 512 + j] = f2bf(gv);
          }
        }
    } else if (gate == 3) {
#pragma unroll
      for (int rt = 0; rt < 2; ++rt)
#pragma unroll
        for (int rr = 0; rr < 4; ++rr) {
          const int row = rt * 16 + kc * 4 + rr;
#pragma unroll
          for (int ct = 0; ct < 16; ++ct) {
            const int j = (wv * 256 + ct * 16 + c16) & 511;
            HB[row * 512 + j] = f2bf(acc[rt][ct][rr]);
          }
        }
    }
    __syncthreads();

    // ---- cell0 combine (waves 4,5 hold xn): h1 -> A0 ins-area (swizzled) ----
    if (gate == 2) {
#pragma unroll
      for (int rt = 0; rt < 2; ++rt)
#pragma unroll
        for (int rr = 0; rr < 4; ++rr) {
          const int row = rt * 16 + kc * 4 + rr;
          const int sw = (row & 7) << 3;
#pragma unroll
          for (int ct = 0; ct < 16; ++ct) {
            const int j = (wv * 256 + ct * 16 + c16) & 511;
            float r = bf2f(RB[row * 512 + j]);
            float z = bf2f(ZB[row * 512 + j]);
            float hn = bf2f(HB[row * 512 + j]);
            float hin = bf2f(A0[row * 1024 + ((512 + j) ^ sw)]);
            float h1 = (1.f - z) * tanhf(acc[rt][ct][rr] + r * hn) + z * hin;
            A0[row * 1024 + (j ^ sw)] = f2bf(h1);
          }
        }
    }
    __syncthreads();

    // ---- cell1 GEMM: acc = h1(32x512) @ W1p-cols ----
#pragma unroll
    for (int rt = 0; rt < 2; ++rt)
#pragma unroll
      for (int ct = 0; ct < 16; ++ct) acc[rt][ct] = (f32x4){0.f, 0.f, 0.f, 0.f};
    for (int kb = 0; kb < 16; ++kb) {
      const int k = kb * 32 + kc * 8;
      short8 a0 = *(const short8*)&A0[c16 * 1024 + (k ^ sw0)];
      short8 a1 = *(const short8*)&A0[(16 + c16) * 1024 + (k ^ sw0)];
#pragma unroll
      for (int ct = 0; ct < 16; ++ct) {
        const int col = wv * 256 + ct * 16 + c16;
        short8 bf = *(const short8*)&W1p[(size_t)col * 512 + k];
        acc[0][ct] = __builtin_amdgcn_mfma_f32_16x16x32_bf16(a0, bf, acc[0][ct], 0, 0, 0);
        acc[1][ct] = __builtin_amdgcn_mfma_f32_16x16x32_bf16(a1, bf, acc[1][ct], 0, 0, 0);
      }
    }
    __syncthreads();

    // ---- cell1: bias + stats ----
#pragma unroll
    for (int ct = 0; ct < 16; ++ct) {
      const int col = wv * 256 + ct * 16 + c16;
      const int j = col & 511;
      float bs = (gate == 3) ? bh_n[512 + j] : bi[1536 + col];
#pragma unroll
      for (int rt = 0; rt < 2; ++rt)
#pragma unroll
        for (int rr = 0; rr < 4; ++rr) acc[rt][ct][rr] += bs;
    }
    if (gate < 2) {
#pragma unroll
      for (int rt = 0; rt < 2; ++rt)
#pragma unroll
        for (int rr = 0; rr < 4; ++rr) {
          float s = 0.f, q = 0.f;
#pragma unroll
          for (int ct = 0; ct < 16; ++ct) { float v = acc[rt][ct][rr]; s += v; q += v * v; }
#pragma unroll
          for (int o = 8; o >= 1; o >>= 1) { s += __shfl_xor(s, o); q += __shfl_xor(q, o); }
          if (c16 == 0) {
            const int row = rt * 16 + kc * 4 + rr;
            st1[gate * 128 + row * 4 + half * 2 + 0] = s;
            st1[gate * 128 + row * 4 + half * 2 + 1] = q;
          }
        }
    }
    __syncthreads();

    // ---- cell1 gates ----
    if (gate < 2) {
#pragma unroll
      for (int rt = 0; rt < 2; ++rt)
#pragma unroll
        for (int rr = 0; rr < 4; ++rr) {
          const int row = rt * 16 + kc * 4 + rr;
          float S = st1[gate * 128 + row * 4 + 0] + st1[gate * 128 + row * 4 + 2];
          float Q = st1[gate * 128 + row * 4 + 1] + st1[gate * 128 + row * 4 + 3];
          float m = S * (1.f / 512.f);
          float vv = Q * (1.f / 512.f) - m * m;
          float ir = rsqrtf(vv + 1e-6f);
#pragma unroll
          for (int ct = 0; ct < 16; ++ct) {
            const int col = wv * 256 + ct * 16 + c16;
            const int j = col & 511;
            float gv = sigf((acc[rt][ct][rr] - m) * ir * ln_s[1024 + gate * 512 + j] +
                            ln_b[1024 + gate * 512 + j]);
            ((gate == 0) ? RB : ZB)[row * 512 + j] = f2bf(gv);
          }
        }
    } else if (gate == 3) {
#pragma unroll
      for (int rt = 0; rt < 2; ++rt)
#pragma unroll
        for (int rr = 0; rr < 4; ++rr) {
          const int row = rt * 16 + kc * 4 + rr;
#pragma unroll
          for (int ct = 0; ct < 16; ++ct) {
            const int j = (wv * 256 + ct * 16 + c16) & 511;
            HB[row * 512 + j] = f2bf(acc[rt][ct][rr]);
          }
        }
    }
    __syncthreads();

    // ---- cell1 combine -> ys[t,b] (+out at t=511) ----
    if (gate == 2) {
#pragma unroll
      for (int rt = 0; rt < 2; ++rt)
#pragma unroll
        for (int rr = 0; rr < 4; ++rr) {
          const int row = rt * 16 + kc * 4 + rr;
          const int sw = (row & 7) << 3;
          const u32 m = g * 32 + (u32)row;
          if (m >= M) continue;
          const u32 e = bucket[gb + row];
          const int t = (int)((e >> 7) & 511), b = (int)(e & 127);
          float* yrow = ys + (size_t)t * (BB * HH) + (size_t)b * HH;
#pragma unroll
          for (int ct = 0; ct < 16; ++ct) {
            const int j = (wv * 256 + ct * 16 + c16) & 511;
            float r = bf2f(RB[row * 512 + j]);
            float z = bf2f(ZB[row * 512 + j]);
            float hn = bf2f(HB[row * 512 + j]);
            float h1v = bf2f(A0[row * 1024 + (j ^ sw)]);
            float h2 = (1.f - z) * tanhf(acc[rt][ct][rr] + r * hn) + z * h1v;
            yrow[j] = h2;
            if (t == TT - 1) out[(size_t)b * HH + j] = h2;
          }
        }
    }
    __syncthreads();
  }
}

// ---------------- cleanup: cells with d >= RCAP (normally zero) ----------------
__global__ __launch_bounds__(256, 1) void cleanup_kernel(
    const float* __restrict__ ins, const void* __restrict__ resets,
    const unsigned* __restrict__ cnt, const float* __restrict__ bi,
    const float* __restrict__ bh_n, const float* __restrict__ ln_s,
    const float* __restrict__ ln_b, const short* __restrict__ W0p,
    const short* __restrict__ W1p, float* __restrict__ out) {
  __shared__ float pre[2048];
  __shared__ float hbuf[512];
  __shared__ float red[4][4];
  const int b = blockIdx.x, tid = threadIdx.x;
  const int wv = tid >> 6, l = tid & 63;
  const int rmode = (int)cnt[FLAG_WORD];
  float* ys = out + BB * HH;
  int d = 0;
  for (int t = 0; t < TT; ++t) {
    bool rs = rmode ? (((const int*)resets)[t * BB + b] != 0)
                    : (((const unsigned char*)resets)[t * BB + b] != 0);
    d = (t == 0 || rs) ? 0 : d + 1;
    if (d < RCAP) continue;
    const float* hin = ys + (size_t)(t - 1) * (BB * HH) + (size_t)b * HH;
    const float* insr = ins + (size_t)t * (BB * HH) + (size_t)b * HH;
    for (int c = tid; c < 2048; c += 256) {
      float s = 0.f;
      const short* w = W0p + (size_t)c * 1024;
      for (int k = 0; k < 512; ++k) s += insr[k] * bf2f(w[k]);
      for (int k = 0; k < 512; ++k) s += hin[k] * bf2f(w[512 + k]);
      pre[c] = s;
    }
    __syncthreads();
    float s0 = 0, q0 = 0, s1 = 0, q1 = 0;
    for (int j = tid; j < 512; j += 256) {
      float a = pre[j] + bi[j]; s0 += a; q0 += a * a;
      float c2 = pre[512 + j] + bi[512 + j]; s1 += c2; q1 += c2 * c2;
    }
#pragma unroll
    for (int o = 32; o >= 1; o >>= 1) {
      s0 += __shfl_xor(s0, o); q0 += __shfl_xor(q0, o);
      s1 += __shfl_xor(s1, o); q1 += __shfl_xor(q1, o);
    }
    if (l == 0) { red[wv][0] = s0; red[wv][1] = q0; red[wv][2] = s1; red[wv][3] = q1; }
    __syncthreads();
    float S0 = red[0][0] + red[1][0] + red[2][0] + red[3][0];
    float Q0 = red[0][1] + red[1][1] + red[2][1] + red[3][1];
    float S1 = red[0][2] + red[1][2] + red[2][2] + red[3][2];
    float Q1 = red[0][3] + red[1][3] + red[2][3] + red[3][3];
    float mr = S0 / 512.f, vr = Q0 / 512.f - mr * mr, ir = rsqrtf(vr + 1e-6f);
    float mz = S1 / 512.f, vz = Q1 / 512.f - mz * mz, iz = rsqrtf(vz + 1e-6f);
    __syncthreads();
    for (int j = tid; j < 512; j += 256) {
      float rg = sigf((pre[j] + bi[j] - mr) * ir * ln_s[j] + ln_b[j]);
      float zg = sigf((pre[512 + j] + bi[512 + j] - mz) * iz * ln_s[512 + j] + ln_b[512 + j]);
      float nn = tanhf(pre[1024 + j] + bi[1024 + j] + rg * (pre[1536 + j] + bh_n[j]));
      hbuf[j] = (1.f - zg) * nn + zg * hin[j];
    }
    __syncthreads();
    for (int c = tid; c < 2048; c += 256) {
      float s = 0.f;
      const short* w = W1p + (size_t)c * 512;
      for (int k = 0; k < 512; ++k) s += hbuf[k] * bf2f(w[k]);
      pre[c] = s;
    }
    __syncthreads();
    s0 = 0; q0 = 0; s1 = 0; q1 = 0;
    for (int j = tid; j < 512; j += 256) {
      float a = pre[j] + bi[1536 + j]; s0 += a; q0 += a * a;
      float c2 = pre[512 + j] + bi[2048 + j]; s1 += c2; q1 += c2 * c2;
    }
#pragma unroll
    for (int o = 32; o >= 1; o >>= 1) {
      s0 += __shfl_xor(s0, o); q0 += __shfl_xor(q0, o);
      s1 += __shfl_xor(s1, o); q1 += __shfl_xor(q1, o);
    }
    if (l == 0) { red[wv][0] = s0; red[wv][1] = q0; red[wv][2] = s1; red[wv][3] = q1; }
    __syncthreads();
    S0 = red[0][0] + red[1][0] + red[2][0] + red[3][0];
    Q0 = red[0][1] + red[1][1] + red[2][1] + red[3][1];
    S1 = red[0][2] + red[1][2] + red[2][2] + red[3][2];
    Q1 = red[0][3] + red[1][3] + red[2][3] + red[3][3];
    mr = S0 / 512.f; vr = Q0 / 512.f - mr * mr; ir = rsqrtf(vr + 1e-6f);
    mz = S1 / 512.f; vz = Q1 / 512.f - mz * mz; iz = rsqrtf(vz + 1e-6f);
    __syncthreads();
    for (int j = tid; j < 512; j += 256) {
      float rg = sigf((pre[j] + bi[1536 + j] - mr) * ir * ln_s[1024 + j] + ln_b[1024 + j]);
      float zg = sigf((pre[512 + j] + bi[2048 + j] - mz) * iz * ln_s[1536 + j] + ln_b[1536 + j]);
      float nn = tanhf(pre[1024 + j] + bi[2560 + j] + rg * (pre[1536 + j] + bh_n[512 + j]));
      float h2 = (1.f - zg) * nn + zg * hbuf[j];
      ys[(size_t)t * (BB * HH) + (size_t)b * HH + j] = h2;
      if (t == TT - 1) out[(size_t)b * HH + j] = h2;
    }
    __syncthreads();
  }
}

extern "C" void kernel_launch(void* const* d_in, const int* in_sizes, int n_in,
                              void* d_out, int out_size, void* d_ws, size_t ws_size,
                              hipStream_t stream) {
  const float* ins   = (const float*)d_in[0];
  const void*  rstp  = d_in[1];
  const float* h0    = (const float*)d_in[2];
  const float* Wi    = (const float*)d_in[3];
  const float* bi    = (const float*)d_in[4];
  const float* Wh_rz = (const float*)d_in[5];
  const float* Wh_n  = (const float*)d_in[6];
  const float* bh_n  = (const float*)d_in[7];
  const float* ln_s  = (const float*)d_in[8];
  const float* ln_b  = (const float*)d_in[9];
  (void)in_sizes; (void)n_in; (void)out_size; (void)ws_size;

  char* ws = (char*)d_ws;
  unsigned* cnt = (unsigned*)ws;                       // off[0..RCAP] + flag @32768
  size_t off = 144 * 1024;
  u32*   bucket = (u32*)(ws + off);  off += (size_t)TT * BB * 4;       // 256 KB
  short* W0p    = (short*)(ws + off); off += (size_t)2048 * 1024 * 2;  // 4 MB
  short* W1p    = (short*)(ws + off); off += (size_t)2048 * 512 * 2;   // 2 MB
  // total ws use ~6.5 MB

  hipMemsetAsync(cnt, 0, (FLAG_WORD + 1) * sizeof(unsigned), stream);
  pack_kernel<<<1536, 256, 0, stream>>>(Wi, Wh_rz, Wh_n, rstp, W0p, W1p, cnt);
  prep_kernel<<<1, 128, 0, stream>>>(rstp, cnt, bucket);
  float* outp = (float*)d_out;
  for (int tau = 0; tau < RCAP; ++tau) {
    round_kernel<<<256, 512, 0, stream>>>(tau, ins, rstp, h0, bi, bh_n, ln_s, ln_b,
                                          W0p, W1p, cnt, bucket, outp);
  }
  cleanup_kernel<<<BB, 256, 0, stream>>>(ins, rstp, cnt, bi, bh_n, ln_s, ln_b,
                                         W0p, W1p, outp);
}

// Round 6
// 12585.414 us; speedup vs baseline: 1.8660x; 1.0271x over previous
//
#include <hip/hip_runtime.h>
#include <hip/hip_bf16.h>

// ScannedRNN: 2-cell LayerNorm-GRU scan. T=512, B=128, H=512.
// Reset-bucketed rounds (R5 structure) + WAVE-COALESCED TILED WEIGHTS:
// W stored as [colTile=col/16][kb=k/32][c16][kc][8] so each MFMA B-load is
// one contiguous 1KB block per wave (was 16x 64B line-splits at 2KB stride).

#define TT 512
#define BB 128
#define HH 512
#define RCAP 24
#define FLAG_WORD 32768

typedef __attribute__((ext_vector_type(8))) short short8;
typedef __attribute__((ext_vector_type(4))) float f32x4;
typedef unsigned int u32;

__device__ __forceinline__ short f2bf(float f) {
  unsigned u = __float_as_uint(f);
  unsigned r = (u + 0x7fffu + ((u >> 16) & 1u)) >> 16;
  return (short)r;
}
__device__ __forceinline__ float bf2f(short s) {
  return __uint_as_float(((unsigned)(unsigned short)s) << 16);
}
__device__ __forceinline__ float sigf(float x) { return 1.f / (1.f + __expf(-x)); }

// tiled weight index: W0 (K=1024): tile=(col>>4)*32+(k>>5); W1 (K=512): (col>>4)*16+(k>>5)
__device__ __forceinline__ size_t w0idx(int col, int k) {
  return (size_t)((col >> 4) * 32 + (k >> 5)) * 512 + (col & 15) * 32 + (k & 31);
}
__device__ __forceinline__ size_t w1idx(int col, int k) {
  return (size_t)((col >> 4) * 16 + (k >> 5)) * 512 + (col & 15) * 32 + (k & 31);
}

// ---------------- pack: weights f32 -> bf16, TILED layout ----------------
// logical W0 [2048 cols][1024 k]: cols 0..511 r, 512..1023 z, 1024..1535 xn
//   (ins-half only), 1536..2047 hn (h-half only); k<512 ins, k>=512 h.
// logical W1 [2048 cols][512 k]: r,z = Wi1+Whrz1 folded; xn = Wi1_n; hn = Whn1.
__global__ void pack_kernel(const float* __restrict__ Wi, const float* __restrict__ Wh_rz,
                            const float* __restrict__ Wh_n, const void* __restrict__ resets,
                            short* __restrict__ W0p, short* __restrict__ W1p,
                            unsigned* __restrict__ cnt) {
  int gid = blockIdx.x * 256 + threadIdx.x;
  if (gid == 0) {
    const unsigned char* rb = (const unsigned char*)resets;
    unsigned intmode = 1u;
    for (int i = 1; i < 4096; ++i) {
      if ((i & 3) && rb[i]) { intmode = 0u; break; }
    }
    cnt[FLAG_WORD] = intmode;
  }
  const int n0 = 2048 * 128;
  const int n1 = 2048 * 64;
  if (gid < n0) {
    int col = gid & 2047, kb = (gid >> 11) * 8;
    int reg = col >> 9, j = col & 511;
    short8 o;
#pragma unroll
    for (int i = 0; i < 8; ++i) {
      int k = kb + i; float v;
      if (reg == 0)      v = (k < 512) ? Wi[(size_t)k * 1536 + j]        : Wh_rz[(size_t)(k - 512) * 1024 + j];
      else if (reg == 1) v = (k < 512) ? Wi[(size_t)k * 1536 + 512 + j]  : Wh_rz[(size_t)(k - 512) * 1024 + 512 + j];
      else if (reg == 2) v = (k < 512) ? Wi[(size_t)k * 1536 + 1024 + j] : 0.f;
      else               v = (k < 512) ? 0.f                             : Wh_n[(size_t)(k - 512) * 512 + j];
      o[i] = f2bf(v);
    }
    *(short8*)&W0p[w0idx(col, kb)] = o;
  } else if (gid < n0 + n1) {
    int g = gid - n0;
    int col = g & 2047, kb = (g >> 11) * 8;
    int reg = col >> 9, j = col & 511;
    const float* Wi1  = Wi + (size_t)512 * 1536;
    const float* Wrz1 = Wh_rz + (size_t)512 * 1024;
    const float* Wn1  = Wh_n + (size_t)512 * 512;
    short8 o;
#pragma unroll
    for (int i = 0; i < 8; ++i) {
      int k = kb + i; float v;
      if (reg == 0)      v = Wi1[(size_t)k * 1536 + j] + Wrz1[(size_t)k * 1024 + j];
      else if (reg == 1) v = Wi1[(size_t)k * 1536 + 512 + j] + Wrz1[(size_t)k * 1024 + 512 + j];
      else if (reg == 2) v = Wi1[(size_t)k * 1536 + 1024 + j];
      else               v = Wn1[(size_t)k * 512 + j];
      o[i] = f2bf(v);
    }
    *(short8*)&W1p[w1idx(col, kb)] = o;
  }
}

// ---------------- prep: bucket cells by d (single WG) ----------------
__global__ void prep_kernel(const void* __restrict__ resets, unsigned* __restrict__ cnt,
                            u32* __restrict__ bucket) {
  __shared__ u32 hist[RCAP + 1];
  __shared__ u32 cur[RCAP + 1];
  const int tid = threadIdx.x;
  const int rmode = (int)cnt[FLAG_WORD];
  const unsigned char* r8 = (const unsigned char*)resets;
  const int* r32 = (const int*)resets;
  if (tid <= RCAP) hist[tid] = 0;
  __syncthreads();
  if (tid < BB) {
    int d = 0;
    for (int t = 0; t < TT; ++t) {
      bool rs = rmode ? (r32[t * BB + tid] != 0) : (r8[t * BB + tid] != 0);
      d = (t == 0 || rs) ? 0 : d + 1;
      int dd = d < RCAP ? d : RCAP;
      atomicAdd(&hist[dd], 1u);
    }
  }
  __syncthreads();
  if (tid == 0) {
    u32 acc = 0;
    for (int i = 0; i <= RCAP; ++i) { u32 h = hist[i]; cur[i] = acc; cnt[i] = acc; acc += h; }
  }
  __syncthreads();
  if (tid < BB) {
    int d = 0;
    for (int t = 0; t < TT; ++t) {
      bool rs = rmode ? (r32[t * BB + tid] != 0) : (r8[t * BB + tid] != 0);
      d = (t == 0 || rs) ? 0 : d + 1;
      if (d < RCAP) {
        u32 pos = atomicAdd(&cur[d], 1u);
        bucket[pos] = ((u32)t << 7) | (u32)tid;
      }
    }
  }
}

// ---------------- round kernel: all cells at distance tau ----------------
__global__ __launch_bounds__(512, 2) void round_kernel(
    int tau, const float* __restrict__ ins, const void* __restrict__ resets,
    const float* __restrict__ h0, const float* __restrict__ bi,
    const float* __restrict__ bh_n, const float* __restrict__ ln_s,
    const float* __restrict__ ln_b, const short* __restrict__ W0p,
    const short* __restrict__ W1p, const unsigned* __restrict__ cnt,
    const u32* __restrict__ bucket, float* __restrict__ out) {
  __shared__ short lds[81920];          // 160 KB exactly
  short* A0 = lds;                      // [32][1024] bf16, xor-swizzled rows
  short* RB = lds + 32768;              // [32][512] r-gate (later r1)
  short* ZB = lds + 49152;              // [32][512] z-gate (later z1)
  short* HB = lds + 65536;              // [32][512] hn (later hn1)
  float* st0 = (float*)lds;             // 256 f32 stats cell0 (row0 ins area, dead then)
  float* st1 = (float*)(lds + 512);     // 256 f32 stats cell1

  const int tid = threadIdx.x;
  const int l = tid & 63, wv = tid >> 6, c16 = l & 15, kc = l >> 4;
  const int gate = wv >> 1, half = wv & 1;
  const int rmode = (int)cnt[FLAG_WORD];
  const u32 boff = cnt[tau];
  const u32 M = cnt[tau + 1] - boff;
  float* ys = out + BB * HH;
  const int sw0 = (c16 & 7) << 3;       // A-row swizzle for rows c16 and 16+c16
  const int lane16 = c16 * 32 + kc * 8; // within-tile offset for tiled W loads

  for (u32 g = blockIdx.x; g * 32 < M; g += gridDim.x) {
    const u32 gb = boff + g * 32;
    __syncthreads();   // protect LDS reuse across groups

    // ---- stage A0: row = [ins(t,b) | h_in] bf16, swizzled ----
    {
      const int row = tid >> 4, part = tid & 15;
      const u32 m = g * 32 + (u32)row;
      u32 e = (m < M) ? bucket[gb + row] : 0xFFFFFFFFu;
      const int t = (int)((e >> 7) & 511), b = (int)(e & 127);
      const int sw = (row & 7) << 3;
      if (e == 0xFFFFFFFFu) {
        const int k0 = part * 64;
        short8 z = {};
#pragma unroll
        for (int gg = 0; gg < 8; ++gg)
          *(short8*)&A0[row * 1024 + ((k0 + gg * 8) ^ sw)] = z;
      } else if (part < 8) {            // ins half, k in [0,512)
        const int k0 = part * 64;
        const float* src = ins + (size_t)t * (BB * HH) + (size_t)b * HH + k0;
#pragma unroll
        for (int gg = 0; gg < 8; ++gg) {
          float4 u0 = *(const float4*)(src + gg * 8);
          float4 u1 = *(const float4*)(src + gg * 8 + 4);
          short8 v;
          v[0] = f2bf(u0.x); v[1] = f2bf(u0.y); v[2] = f2bf(u0.z); v[3] = f2bf(u0.w);
          v[4] = f2bf(u1.x); v[5] = f2bf(u1.y); v[6] = f2bf(u1.z); v[7] = f2bf(u1.w);
          *(short8*)&A0[row * 1024 + ((k0 + gg * 8) ^ sw)] = v;
        }
      } else {                          // h half, k in [512,1024)
        const int k0 = (part - 8) * 64;
        const float* src = nullptr;
        bool zero = false;
        if (tau > 0) {
          src = ys + (size_t)(t - 1) * (BB * HH) + (size_t)b * HH + k0;
        } else {
          bool rs = rmode ? (((const int*)resets)[t * BB + b] != 0)
                          : (((const unsigned char*)resets)[t * BB + b] != 0);
          if (rs) zero = true; else src = h0 + (size_t)b * HH + k0;  // t==0 here
        }
#pragma unroll
        for (int gg = 0; gg < 8; ++gg) {
          short8 v = {};
          if (!zero) {
            float4 u0 = *(const float4*)(src + gg * 8);
            float4 u1 = *(const float4*)(src + gg * 8 + 4);
            v[0] = f2bf(u0.x); v[1] = f2bf(u0.y); v[2] = f2bf(u0.z); v[3] = f2bf(u0.w);
            v[4] = f2bf(u1.x); v[5] = f2bf(u1.y); v[6] = f2bf(u1.z); v[7] = f2bf(u1.w);
          }
          *(short8*)&A0[row * 1024 + ((512 + k0 + gg * 8) ^ sw)] = v;
        }
      }
    }
    __syncthreads();

    // ---- cell0 GEMM: acc[rt][ct] = A(32x1024) @ W0-cols (tiled, coalesced) ----
    f32x4 acc[2][16];
#pragma unroll
    for (int rt = 0; rt < 2; ++rt)
#pragma unroll
      for (int ct = 0; ct < 16; ++ct) acc[rt][ct] = (f32x4){0.f, 0.f, 0.f, 0.f};
    for (int kb = 0; kb < 32; ++kb) {
      const int k = kb * 32 + kc * 8;
      short8 a0 = *(const short8*)&A0[c16 * 1024 + (k ^ sw0)];
      short8 a1 = *(const short8*)&A0[(16 + c16) * 1024 + (k ^ sw0)];
#pragma unroll
      for (int ct = 0; ct < 16; ++ct) {
        // tiled: one contiguous 1KB block per wave per (ct,kb)
        const short* bp = W0p + (size_t)((wv * 16 + ct) * 32 + kb) * 512 + lane16;
        short8 bf = *(const short8*)bp;
        acc[0][ct] = __builtin_amdgcn_mfma_f32_16x16x32_bf16(a0, bf, acc[0][ct], 0, 0, 0);
        acc[1][ct] = __builtin_amdgcn_mfma_f32_16x16x32_bf16(a1, bf, acc[1][ct], 0, 0, 0);
      }
    }
    __syncthreads();   // GEMM done; A0 row0-ins reusable for stats

    // ---- cell0: bias add + LN stats (gates r,z) ----
#pragma unroll
    for (int ct = 0; ct < 16; ++ct) {
      const int col = wv * 256 + ct * 16 + c16;
      const int j = col & 511;
      float bs = (gate == 3) ? bh_n[j] : bi[col];
#pragma unroll
      for (int rt = 0; rt < 2; ++rt)
#pragma unroll
        for (int rr = 0; rr < 4; ++rr) acc[rt][ct][rr] += bs;
    }
    if (gate < 2) {
#pragma unroll
      for (int rt = 0; rt < 2; ++rt)
#pragma unroll
        for (int rr = 0; rr < 4; ++rr) {
          float s = 0.f, q = 0.f;
#pragma unroll
          for (int ct = 0; ct < 16; ++ct) { float v = acc[rt][ct][rr]; s += v; q += v * v; }
#pragma unroll
          for (int o = 8; o >= 1; o >>= 1) { s += __shfl_xor(s, o); q += __shfl_xor(q, o); }
          if (c16 == 0) {
            const int row = rt * 16 + kc * 4 + rr;
            st0[gate * 128 + row * 4 + half * 2 + 0] = s;
            st0[gate * 128 + row * 4 + half * 2 + 1] = q;
          }
        }
    }
    __syncthreads();

    // ---- cell0 gates ----
    if (gate < 2) {
#pragma unroll
      for (int rt = 0; rt < 2; ++rt)
#pragma unroll
        for (int rr = 0; rr < 4; ++rr) {
          const int row = rt * 16 + kc * 4 + rr;
          float S = st0[gate * 128 + row * 4 + 0] + st0[gate * 128 + row * 4 + 2];
          float Q = st0[gate * 128 + row * 4 + 1] + st0[gate * 128 + row * 4 + 3];
          float m = S * (1.f / 512.f);
          float vv = Q * (1.f / 512.f) - m * m;
          float ir = rsqrtf(vv + 1e-6f);
#pragma unroll
          for (int ct = 0; ct < 16; ++ct) {
            const int col = wv * 256 + ct * 16 + c16;
            const int j = col & 511;
            float gv = sigf((acc[rt][ct][rr] - m) * ir * ln_s[gate * 512 + j] + ln_b[gate * 512 + j]);
            ((gate == 0) ? RB : ZB)[row * 512 + j] = f2bf(gv);
          }
        }
    } else if (gate == 3) {
#pragma unroll
      for (int rt = 0; rt < 2; ++rt)
#pragma unroll
        for (int rr = 0; rr < 4; ++rr) {
          const int row = rt * 16 + kc * 4 + rr;
#pragma unroll
          for (int ct = 0; ct < 16; ++ct) {
            const int j = (wv * 256 + ct * 16 + c16) & 511;
            HB[row * 512 + j] = f2bf(acc[rt][ct][rr]);
          }
        }
    }
    __syncthreads();

    // ---- cell0 combine (waves 4,5 hold xn): h1 -> A0 ins-area (swizzled) ----
    if (gate == 2) {
#pragma unroll
      for (int rt = 0; rt < 2; ++rt)
#pragma unroll
        for (int rr = 0; rr < 4; ++rr) {
          const int row = rt * 16 + kc * 4 + rr;
          const int sw = (row & 7) << 3;
#pragma unroll
          for (int ct = 0; ct < 16; ++ct) {
            const int j = (wv * 256 + ct * 16 + c16) & 511;
            float r = bf2f(RB[row * 512 + j]);
            float z = bf2f(ZB[row * 512 + j]);
            float hn = bf2f(HB[row * 512 + j]);
            float hin = bf2f(A0[row * 1024 + ((512 + j) ^ sw)]);
            float h1 = (1.f - z) * tanhf(acc[rt][ct][rr] + r * hn) + z * hin;
            A0[row * 1024 + (j ^ sw)] = f2bf(h1);
          }
        }
    }
    __syncthreads();

    // ---- cell1 GEMM: acc = h1(32x512) @ W1-cols (tiled) ----
#pragma unroll
    for (int rt = 0; rt < 2; ++rt)
#pragma unroll
      for (int ct = 0; ct < 16; ++ct) acc[rt][ct] = (f32x4){0.f, 0.f, 0.f, 0.f};
    for (int kb = 0; kb < 16; ++kb) {
      const int k = kb * 32 + kc * 8;
      short8 a0 = *(const short8*)&A0[c16 * 1024 + (k ^ sw0)];
      short8 a1 = *(const short8*)&A0[(16 + c16) * 1024 + (k ^ sw0)];
#pragma unroll
      for (int ct = 0; ct < 16; ++ct) {
        const short* bp = W1p + (size_t)((wv * 16 + ct) * 16 + kb) * 512 + lane16;
        short8 bf = *(const short8*)bp;
        acc[0][ct] = __builtin_amdgcn_mfma_f32_16x16x32_bf16(a0, bf, acc[0][ct], 0, 0, 0);
        acc[1][ct] = __builtin_amdgcn_mfma_f32_16x16x32_bf16(a1, bf, acc[1][ct], 0, 0, 0);
      }
    }
    __syncthreads();

    // ---- cell1: bias + stats ----
#pragma unroll
    for (int ct = 0; ct < 16; ++ct) {
      const int col = wv * 256 + ct * 16 + c16;
      const int j = col & 511;
      float bs = (gate == 3) ? bh_n[512 + j] : bi[1536 + col];
#pragma unroll
      for (int rt = 0; rt < 2; ++rt)
#pragma unroll
        for (int rr = 0; rr < 4; ++rr) acc[rt][ct][rr] += bs;
    }
    if (gate < 2) {
#pragma unroll
      for (int rt = 0; rt < 2; ++rt)
#pragma unroll
        for (int rr = 0; rr < 4; ++rr) {
          float s = 0.f, q = 0.f;
#pragma unroll
          for (int ct = 0; ct < 16; ++ct) { float v = acc[rt][ct][rr]; s += v; q += v * v; }
#pragma unroll
          for (int o = 8; o >= 1; o >>= 1) { s += __shfl_xor(s, o); q += __shfl_xor(q, o); }
          if (c16 == 0) {
            const int row = rt * 16 + kc * 4 + rr;
            st1[gate * 128 + row * 4 + half * 2 + 0] = s;
            st1[gate * 128 + row * 4 + half * 2 + 1] = q;
          }
        }
    }
    __syncthreads();

    // ---- cell1 gates ----
    if (gate < 2) {
#pragma unroll
      for (int rt = 0; rt < 2; ++rt)
#pragma unroll
        for (int rr = 0; rr < 4; ++rr) {
          const int row = rt * 16 + kc * 4 + rr;
          float S = st1[gate * 128 + row * 4 + 0] + st1[gate * 128 + row * 4 + 2];
          float Q = st1[gate * 128 + row * 4 + 1] + st1[gate * 128 + row * 4 + 3];
          float m = S * (1.f / 512.f);
          float vv = Q * (1.f / 512.f) - m * m;
          float ir = rsqrtf(vv + 1e-6f);
#pragma unroll
          for (int ct = 0; ct < 16; ++ct) {
            const int col = wv * 256 + ct * 16 + c16;
            const int j = col & 511;
            float gv = sigf((acc[rt][ct][rr] - m) * ir * ln_s[1024 + gate * 512 + j] +
                            ln_b[1024 + gate * 512 + j]);
            ((gate == 0) ? RB : ZB)[row * 512 + j] = f2bf(gv);
          }
        }
    } else if (gate == 3) {
#pragma unroll
      for (int rt = 0; rt < 2; ++rt)
#pragma unroll
        for (int rr = 0; rr < 4; ++rr) {
          const int row = rt * 16 + kc * 4 + rr;
#pragma unroll
          for (int ct = 0; ct < 16; ++ct) {
            const int j = (wv * 256 + ct * 16 + c16) & 511;
            HB[row * 512 + j] = f2bf(acc[rt][ct][rr]);
          }
        }
    }
    __syncthreads();

    // ---- cell1 combine -> ys[t,b] (+out at t=511) ----
    if (gate == 2) {
#pragma unroll
      for (int rt = 0; rt < 2; ++rt)
#pragma unroll
        for (int rr = 0; rr < 4; ++rr) {
          const int row = rt * 16 + kc * 4 + rr;
          const int sw = (row & 7) << 3;
          const u32 m = g * 32 + (u32)row;
          if (m >= M) continue;
          const u32 e = bucket[gb + row];
          const int t = (int)((e >> 7) & 511), b = (int)(e & 127);
          float* yrow = ys + (size_t)t * (BB * HH) + (size_t)b * HH;
#pragma unroll
          for (int ct = 0; ct < 16; ++ct) {
            const int j = (wv * 256 + ct * 16 + c16) & 511;
            float r = bf2f(RB[row * 512 + j]);
            float z = bf2f(ZB[row * 512 + j]);
            float hn = bf2f(HB[row * 512 + j]);
            float h1v = bf2f(A0[row * 1024 + (j ^ sw)]);
            float h2 = (1.f - z) * tanhf(acc[rt][ct][rr] + r * hn) + z * h1v;
            yrow[j] = h2;
            if (t == TT - 1) out[(size_t)b * HH + j] = h2;
          }
        }
    }
    __syncthreads();
  }
}

// ---------------- cleanup: cells with d >= RCAP (normally zero) ----------------
__global__ __launch_bounds__(256, 1) void cleanup_kernel(
    const float* __restrict__ ins, const void* __restrict__ resets,
    const unsigned* __restrict__ cnt, const float* __restrict__ bi,
    const float* __restrict__ bh_n, const float* __restrict__ ln_s,
    const float* __restrict__ ln_b, const short* __restrict__ W0p,
    const short* __restrict__ W1p, float* __restrict__ out) {
  __shared__ float pre[2048];
  __shared__ float hbuf[512];
  __shared__ float red[4][4];
  const int b = blockIdx.x, tid = threadIdx.x;
  const int wv = tid >> 6, l = tid & 63;
  const int rmode = (int)cnt[FLAG_WORD];
  float* ys = out + BB * HH;
  int d = 0;
  for (int t = 0; t < TT; ++t) {
    bool rs = rmode ? (((const int*)resets)[t * BB + b] != 0)
                    : (((const unsigned char*)resets)[t * BB + b] != 0);
    d = (t == 0 || rs) ? 0 : d + 1;
    if (d < RCAP) continue;
    const float* hin = ys + (size_t)(t - 1) * (BB * HH) + (size_t)b * HH;
    const float* insr = ins + (size_t)t * (BB * HH) + (size_t)b * HH;
    for (int c = tid; c < 2048; c += 256) {
      float s = 0.f;
      for (int k = 0; k < 512; ++k) s += insr[k] * bf2f(W0p[w0idx(c, k)]);
      for (int k = 0; k < 512; ++k) s += hin[k] * bf2f(W0p[w0idx(c, 512 + k)]);
      pre[c] = s;
    }
    __syncthreads();
    float s0 = 0, q0 = 0, s1 = 0, q1 = 0;
    for (int j = tid; j < 512; j += 256) {
      float a = pre[j] + bi[j]; s0 += a; q0 += a * a;
      float c2 = pre[512 + j] + bi[512 + j]; s1 += c2; q1 += c2 * c2;
    }
#pragma unroll
    for (int o = 32; o >= 1; o >>= 1) {
      s0 += __shfl_xor(s0, o); q0 += __shfl_xor(q0, o);
      s1 += __shfl_xor(s1, o); q1 += __shfl_xor(q1, o);
    }
    if (l == 0) { red[wv][0] = s0; red[wv][1] = q0; red[wv][2] = s1; red[wv][3] = q1; }
    __syncthreads();
    float S0 = red[0][0] + red[1][0] + red[2][0] + red[3][0];
    float Q0 = red[0][1] + red[1][1] + red[2][1] + red[3][1];
    float S1 = red[0][2] + red[1][2] + red[2][2] + red[3][2];
    float Q1 = red[0][3] + red[1][3] + red[2][3] + red[3][3];
    float mr = S0 / 512.f, vr = Q0 / 512.f - mr * mr, ir = rsqrtf(vr + 1e-6f);
    float mz = S1 / 512.f, vz = Q1 / 512.f - mz * mz, iz = rsqrtf(vz + 1e-6f);
    __syncthreads();
    for (int j = tid; j < 512; j += 256) {
      float rg = sigf((pre[j] + bi[j] - mr) * ir * ln_s[j] + ln_b[j]);
      float zg = sigf((pre[512 + j] + bi[512 + j] - mz) * iz * ln_s[512 + j] + ln_b[512 + j]);
      float nn = tanhf(pre[1024 + j] + bi[1024 + j] + rg * (pre[1536 + j] + bh_n[j]));
      hbuf[j] = (1.f - zg) * nn + zg * hin[j];
    }
    __syncthreads();
    for (int c = tid; c < 2048; c += 256) {
      float s = 0.f;
      for (int k = 0; k < 512; ++k) s += hbuf[k] * bf2f(W1p[w1idx(c, k)]);
      pre[c] = s;
    }
    __syncthreads();
    s0 = 0; q0 = 0; s1 = 0; q1 = 0;
    for (int j = tid; j < 512; j += 256) {
      float a = pre[j] + bi[1536 + j]; s0 += a; q0 += a * a;
      float c2 = pre[512 + j] + bi[2048 + j]; s1 += c2; q1 += c2 * c2;
    }
#pragma unroll
    for (int o = 32; o >= 1; o >>= 1) {
      s0 += __shfl_xor(s0, o); q0 += __shfl_xor(q0, o);
      s1 += __shfl_xor(s1, o); q1 += __shfl_xor(q1, o);
    }
    if (l == 0) { red[wv][0] = s0; red[wv][1] = q0; red[wv][2] = s1; red[wv][3] = q1; }
    __syncthreads();
    S0 = red[0][0] + red[1][0] + red[2][0] + red[3][0];
    Q0 = red[0][1] + red[1][1] + red[2][1] + red[3][1];
    S1 = red[0][2] + red[1][2] + red[2][2] + red[3][2];
    Q1 = red[0][3] + red[1][3] + red[2][3] + red[3][3];
    mr = S0 / 512.f; vr = Q0 / 512.f - mr * mr; ir = rsqrtf(vr + 1e-6f);
    mz = S1 / 512.f; vz = Q1 / 512.f - mz * mz; iz = rsqrtf(vz + 1e-6f);
    __syncthreads();
    for (int j = tid; j < 512; j += 256) {
      float rg = sigf((pre[j] + bi[1536 + j] - mr) * ir * ln_s[1024 + j] + ln_b[1024 + j]);
      float zg = sigf((pre[512 + j] + bi[2048 + j] - mz) * iz * ln_s[1536 + j] + ln_b[1536 + j]);
      float nn = tanhf(pre[1024 + j] + bi[2560 + j] + rg * (pre[1536 + j] + bh_n[512 + j]));
      float h2 = (1.f - zg) * nn + zg * hbuf[j];
      ys[(size_t)t * (BB * HH) + (size_t)b * HH + j] = h2;
      if (t == TT - 1) out[(size_t)b * HH + j] = h2;
    }
    __syncthreads();
  }
}

extern "C" void kernel_launch(void* const* d_in, const int* in_sizes, int n_in,
                              void* d_out, int out_size, void* d_ws, size_t ws_size,
                              hipStream_t stream) {
  const float* ins   = (const float*)d_in[0];
  const void*  rstp  = d_in[1];
  const float* h0    = (const float*)d_in[2];
  const float* Wi    = (const float*)d_in[3];
  const float* bi    = (const float*)d_in[4];
  const float* Wh_rz = (const float*)d_in[5];
  const float* Wh_n  = (const float*)d_in[6];
  const float* bh_n  = (const float*)d_in[7];
  const float* ln_s  = (const float*)d_in[8];
  const float* ln_b  = (const float*)d_in[9];
  (void)in_sizes; (void)n_in; (void)out_size; (void)ws_size;

  char* ws = (char*)d_ws;
  unsigned* cnt = (unsigned*)ws;                       // off[0..RCAP] + flag @32768
  size_t off = 144 * 1024;
  u32*   bucket = (u32*)(ws + off);  off += (size_t)TT * BB * 4;       // 256 KB
  short* W0p    = (short*)(ws + off); off += (size_t)2048 * 1024 * 2;  // 4 MB
  short* W1p    = (short*)(ws + off); off += (size_t)2048 * 512 * 2;   // 2 MB
  // total ws use ~6.5 MB

  hipMemsetAsync(cnt, 0, (FLAG_WORD + 1) * sizeof(unsigned), stream);
  pack_kernel<<<1536, 256, 0, stream>>>(Wi, Wh_rz, Wh_n, rstp, W0p, W1p, cnt);
  prep_kernel<<<1, 128, 0, stream>>>(rstp, cnt, bucket);
  float* outp = (float*)d_out;
  for (int tau = 0; tau < RCAP; ++tau) {
    round_kernel<<<256, 512, 0, stream>>>(tau, ins, rstp, h0, bi, bh_n, ln_s, ln_b,
                                          W0p, W1p, cnt, bucket, outp);
  }
  cleanup_kernel<<<BB, 256, 0, stream>>>(ins, rstp, cnt, bi, bh_n, ln_s, ln_b,
                                         W0p, W1p, outp);
}

// Round 7
// 11630.738 us; speedup vs baseline: 2.0191x; 1.0821x over previous
//
#include <hip/hip_runtime.h>
#include <hip/hip_bf16.h>

// ScannedRNN: 2-cell LayerNorm-GRU scan. T=512, B=128, H=512.
// Reset-bucketed rounds + tiled weights + R7: MLP fix.
//  - __launch_bounds__(512,1): 256-VGPR budget (LDS already caps at 1 WG/CU;
//    the old ",2" only crippled the register allocator -> serialized loads).
//  - B-tiles staged 16-at-a-time into a register array: MALL latency paid
//    once per kb-iter, not once per load.
//  - Zero-tile skip: xn cols (h-half zero) run kb<16; hn cols kb>=16.

#define TT 512
#define BB 128
#define HH 512
#define RCAP 24
#define FLAG_WORD 32768

typedef __attribute__((ext_vector_type(8))) short short8;
typedef __attribute__((ext_vector_type(4))) float f32x4;
typedef unsigned int u32;

__device__ __forceinline__ short f2bf(float f) {
  unsigned u = __float_as_uint(f);
  unsigned r = (u + 0x7fffu + ((u >> 16) & 1u)) >> 16;
  return (short)r;
}
__device__ __forceinline__ float bf2f(short s) {
  return __uint_as_float(((unsigned)(unsigned short)s) << 16);
}
__device__ __forceinline__ float sigf(float x) { return 1.f / (1.f + __expf(-x)); }

// tiled weight index: W0 (K=1024): tile=(col>>4)*32+(k>>5); W1 (K=512): (col>>4)*16+(k>>5)
__device__ __forceinline__ size_t w0idx(int col, int k) {
  return (size_t)((col >> 4) * 32 + (k >> 5)) * 512 + (col & 15) * 32 + (k & 31);
}
__device__ __forceinline__ size_t w1idx(int col, int k) {
  return (size_t)((col >> 4) * 16 + (k >> 5)) * 512 + (col & 15) * 32 + (k & 31);
}

// ---------------- pack: weights f32 -> bf16, TILED layout ----------------
__global__ void pack_kernel(const float* __restrict__ Wi, const float* __restrict__ Wh_rz,
                            const float* __restrict__ Wh_n, const void* __restrict__ resets,
                            short* __restrict__ W0p, short* __restrict__ W1p,
                            unsigned* __restrict__ cnt) {
  int gid = blockIdx.x * 256 + threadIdx.x;
  if (gid == 0) {
    const unsigned char* rb = (const unsigned char*)resets;
    unsigned intmode = 1u;
    for (int i = 1; i < 4096; ++i) {
      if ((i & 3) && rb[i]) { intmode = 0u; break; }
    }
    cnt[FLAG_WORD] = intmode;
  }
  const int n0 = 2048 * 128;
  const int n1 = 2048 * 64;
  if (gid < n0) {
    int col = gid & 2047, kb = (gid >> 11) * 8;
    int reg = col >> 9, j = col & 511;
    short8 o;
#pragma unroll
    for (int i = 0; i < 8; ++i) {
      int k = kb + i; float v;
      if (reg == 0)      v = (k < 512) ? Wi[(size_t)k * 1536 + j]        : Wh_rz[(size_t)(k - 512) * 1024 + j];
      else if (reg == 1) v = (k < 512) ? Wi[(size_t)k * 1536 + 512 + j]  : Wh_rz[(size_t)(k - 512) * 1024 + 512 + j];
      else if (reg == 2) v = (k < 512) ? Wi[(size_t)k * 1536 + 1024 + j] : 0.f;
      else               v = (k < 512) ? 0.f                             : Wh_n[(size_t)(k - 512) * 512 + j];
      o[i] = f2bf(v);
    }
    *(short8*)&W0p[w0idx(col, kb)] = o;
  } else if (gid < n0 + n1) {
    int g = gid - n0;
    int col = g & 2047, kb = (g >> 11) * 8;
    int reg = col >> 9, j = col & 511;
    const float* Wi1  = Wi + (size_t)512 * 1536;
    const float* Wrz1 = Wh_rz + (size_t)512 * 1024;
    const float* Wn1  = Wh_n + (size_t)512 * 512;
    short8 o;
#pragma unroll
    for (int i = 0; i < 8; ++i) {
      int k = kb + i; float v;
      if (reg == 0)      v = Wi1[(size_t)k * 1536 + j] + Wrz1[(size_t)k * 1024 + j];
      else if (reg == 1) v = Wi1[(size_t)k * 1536 + 512 + j] + Wrz1[(size_t)k * 1024 + 512 + j];
      else if (reg == 2) v = Wi1[(size_t)k * 1536 + 1024 + j];
      else               v = Wn1[(size_t)k * 512 + j];
      o[i] = f2bf(v);
    }
    *(short8*)&W1p[w1idx(col, kb)] = o;
  }
}

// ---------------- prep: bucket cells by d (single WG) ----------------
__global__ void prep_kernel(const void* __restrict__ resets, unsigned* __restrict__ cnt,
                            u32* __restrict__ bucket) {
  __shared__ u32 hist[RCAP + 1];
  __shared__ u32 cur[RCAP + 1];
  const int tid = threadIdx.x;
  const int rmode = (int)cnt[FLAG_WORD];
  const unsigned char* r8 = (const unsigned char*)resets;
  const int* r32 = (const int*)resets;
  if (tid <= RCAP) hist[tid] = 0;
  __syncthreads();
  if (tid < BB) {
    int d = 0;
    for (int t = 0; t < TT; ++t) {
      bool rs = rmode ? (r32[t * BB + tid] != 0) : (r8[t * BB + tid] != 0);
      d = (t == 0 || rs) ? 0 : d + 1;
      int dd = d < RCAP ? d : RCAP;
      atomicAdd(&hist[dd], 1u);
    }
  }
  __syncthreads();
  if (tid == 0) {
    u32 acc = 0;
    for (int i = 0; i <= RCAP; ++i) { u32 h = hist[i]; cur[i] = acc; cnt[i] = acc; acc += h; }
  }
  __syncthreads();
  if (tid < BB) {
    int d = 0;
    for (int t = 0; t < TT; ++t) {
      bool rs = rmode ? (r32[t * BB + tid] != 0) : (r8[t * BB + tid] != 0);
      d = (t == 0 || rs) ? 0 : d + 1;
      if (d < RCAP) {
        u32 pos = atomicAdd(&cur[d], 1u);
        bucket[pos] = ((u32)t << 7) | (u32)tid;
      }
    }
  }
}

// ---------------- round kernel: all cells at distance tau ----------------
__global__ __launch_bounds__(512, 1) void round_kernel(
    int tau, const float* __restrict__ ins, const void* __restrict__ resets,
    const float* __restrict__ h0, const float* __restrict__ bi,
    const float* __restrict__ bh_n, const float* __restrict__ ln_s,
    const float* __restrict__ ln_b, const short* __restrict__ W0p,
    const short* __restrict__ W1p, const unsigned* __restrict__ cnt,
    const u32* __restrict__ bucket, float* __restrict__ out) {
  __shared__ short lds[81920];          // 160 KB exactly
  short* A0 = lds;                      // [32][1024] bf16, xor-swizzled rows
  short* RB = lds + 32768;              // [32][512] r-gate (later r1)
  short* ZB = lds + 49152;              // [32][512] z-gate (later z1)
  short* HB = lds + 65536;              // [32][512] hn (later hn1)
  float* st0 = (float*)lds;             // 256 f32 stats cell0 (row0 ins area, dead then)
  float* st1 = (float*)(lds + 512);     // 256 f32 stats cell1

  const int tid = threadIdx.x;
  const int l = tid & 63, wv = tid >> 6, c16 = l & 15, kc = l >> 4;
  const int gate = wv >> 1, half = wv & 1;
  const int rmode = (int)cnt[FLAG_WORD];
  const u32 boff = cnt[tau];
  const u32 M = cnt[tau + 1] - boff;
  float* ys = out + BB * HH;
  const int sw0 = (c16 & 7) << 3;       // A-row swizzle for rows c16 and 16+c16
  const int lane16 = c16 * 32 + kc * 8; // within-tile offset for tiled W loads

  for (u32 g = blockIdx.x; g * 32 < M; g += gridDim.x) {
    const u32 gb = boff + g * 32;
    __syncthreads();   // protect LDS reuse across groups

    // ---- stage A0: row = [ins(t,b) | h_in] bf16, swizzled ----
    {
      const int row = tid >> 4, part = tid & 15;
      const u32 m = g * 32 + (u32)row;
      u32 e = (m < M) ? bucket[gb + row] : 0xFFFFFFFFu;
      const int t = (int)((e >> 7) & 511), b = (int)(e & 127);
      const int sw = (row & 7) << 3;
      if (e == 0xFFFFFFFFu) {
        const int k0 = part * 64;
        short8 z = {};
#pragma unroll
        for (int gg = 0; gg < 8; ++gg)
          *(short8*)&A0[row * 1024 + ((k0 + gg * 8) ^ sw)] = z;
      } else if (part < 8) {            // ins half, k in [0,512)
        const int k0 = part * 64;
        const float* src = ins + (size_t)t * (BB * HH) + (size_t)b * HH + k0;
#pragma unroll
        for (int gg = 0; gg < 8; ++gg) {
          float4 u0 = *(const float4*)(src + gg * 8);
          float4 u1 = *(const float4*)(src + gg * 8 + 4);
          short8 v;
          v[0] = f2bf(u0.x); v[1] = f2bf(u0.y); v[2] = f2bf(u0.z); v[3] = f2bf(u0.w);
          v[4] = f2bf(u1.x); v[5] = f2bf(u1.y); v[6] = f2bf(u1.z); v[7] = f2bf(u1.w);
          *(short8*)&A0[row * 1024 + ((k0 + gg * 8) ^ sw)] = v;
        }
      } else {                          // h half, k in [512,1024)
        const int k0 = (part - 8) * 64;
        const float* src = nullptr;
        bool zero = false;
        if (tau > 0) {
          src = ys + (size_t)(t - 1) * (BB * HH) + (size_t)b * HH + k0;
        } else {
          bool rs = rmode ? (((const int*)resets)[t * BB + b] != 0)
                          : (((const unsigned char*)resets)[t * BB + b] != 0);
          if (rs) zero = true; else src = h0 + (size_t)b * HH + k0;  // t==0 here
        }
#pragma unroll
        for (int gg = 0; gg < 8; ++gg) {
          short8 v = {};
          if (!zero) {
            float4 u0 = *(const float4*)(src + gg * 8);
            float4 u1 = *(const float4*)(src + gg * 8 + 4);
            v[0] = f2bf(u0.x); v[1] = f2bf(u0.y); v[2] = f2bf(u0.z); v[3] = f2bf(u0.w);
            v[4] = f2bf(u1.x); v[5] = f2bf(u1.y); v[6] = f2bf(u1.z); v[7] = f2bf(u1.w);
          }
          *(short8*)&A0[row * 1024 + ((512 + k0 + gg * 8) ^ sw)] = v;
        }
      }
    }
    __syncthreads();

    // ---- cell0 GEMM: acc[rt][ct] = A(32x1024) @ W0-cols, B staged 16-wide ----
    f32x4 acc[2][16];
#pragma unroll
    for (int rt = 0; rt < 2; ++rt)
#pragma unroll
      for (int ct = 0; ct < 16; ++ct) acc[rt][ct] = (f32x4){0.f, 0.f, 0.f, 0.f};
    {
      // zero-tile skip: gate2 (xn) has zero h-half -> kb<16; gate3 (hn) kb>=16
      const int kb_lo = (gate == 3) ? 16 : 0;
      const int kb_hi = (gate == 2) ? 16 : 32;
#pragma unroll 1
      for (int kb = kb_lo; kb < kb_hi; ++kb) {
        const int k = kb * 32 + kc * 8;
        short8 a0 = *(const short8*)&A0[c16 * 1024 + (k ^ sw0)];
        short8 a1 = *(const short8*)&A0[(16 + c16) * 1024 + (k ^ sw0)];
        short8 bq[16];
#pragma unroll
        for (int ct = 0; ct < 16; ++ct)
          bq[ct] = *(const short8*)(W0p + (size_t)((wv * 16 + ct) * 32 + kb) * 512 + lane16);
#pragma unroll
        for (int ct = 0; ct < 16; ++ct) {
          acc[0][ct] = __builtin_amdgcn_mfma_f32_16x16x32_bf16(a0, bq[ct], acc[0][ct], 0, 0, 0);
          acc[1][ct] = __builtin_amdgcn_mfma_f32_16x16x32_bf16(a1, bq[ct], acc[1][ct], 0, 0, 0);
        }
      }
    }
    __syncthreads();   // GEMM done; A0 row0-ins reusable for stats

    // ---- cell0: bias add + LN stats (gates r,z) ----
#pragma unroll
    for (int ct = 0; ct < 16; ++ct) {
      const int col = wv * 256 + ct * 16 + c16;
      const int j = col & 511;
      float bs = (gate == 3) ? bh_n[j] : bi[col];
#pragma unroll
      for (int rt = 0; rt < 2; ++rt)
#pragma unroll
        for (int rr = 0; rr < 4; ++rr) acc[rt][ct][rr] += bs;
    }
    if (gate < 2) {
#pragma unroll
      for (int rt = 0; rt < 2; ++rt)
#pragma unroll
        for (int rr = 0; rr < 4; ++rr) {
          float s = 0.f, q = 0.f;
#pragma unroll
          for (int ct = 0; ct < 16; ++ct) { float v = acc[rt][ct][rr]; s += v; q += v * v; }
#pragma unroll
          for (int o = 8; o >= 1; o >>= 1) { s += __shfl_xor(s, o); q += __shfl_xor(q, o); }
          if (c16 == 0) {
            const int row = rt * 16 + kc * 4 + rr;
            st0[gate * 128 + row * 4 + half * 2 + 0] = s;
            st0[gate * 128 + row * 4 + half * 2 + 1] = q;
          }
        }
    }
    __syncthreads();

    // ---- cell0 gates ----
    if (gate < 2) {
#pragma unroll
      for (int rt = 0; rt < 2; ++rt)
#pragma unroll
        for (int rr = 0; rr < 4; ++rr) {
          const int row = rt * 16 + kc * 4 + rr;
          float S = st0[gate * 128 + row * 4 + 0] + st0[gate * 128 + row * 4 + 2];
          float Q = st0[gate * 128 + row * 4 + 1] + st0[gate * 128 + row * 4 + 3];
          float m = S * (1.f / 512.f);
          float vv = Q * (1.f / 512.f) - m * m;
          float ir = rsqrtf(vv + 1e-6f);
#pragma unroll
          for (int ct = 0; ct < 16; ++ct) {
            const int col = wv * 256 + ct * 16 + c16;
            const int j = col & 511;
            float gv = sigf((acc[rt][ct][rr] - m) * ir * ln_s[gate * 512 + j] + ln_b[gate * 512 + j]);
            ((gate == 0) ? RB : ZB)[row * 512 + j] = f2bf(gv);
          }
        }
    } else if (gate == 3) {
#pragma unroll
      for (int rt = 0; rt < 2; ++rt)
#pragma unroll
        for (int rr = 0; rr < 4; ++rr) {
          const int row = rt * 16 + kc * 4 + rr;
#pragma unroll
          for (int ct = 0; ct < 16; ++ct) {
            const int j = (wv * 256 + ct * 16 + c16) & 511;
            HB[row * 512 + j] = f2bf(acc[rt][ct][rr]);
          }
        }
    }
    __syncthreads();

    // ---- cell0 combine (waves 4,5 hold xn): h1 -> A0 ins-area (swizzled) ----
    if (gate == 2) {
#pragma unroll
      for (int rt = 0; rt < 2; ++rt)
#pragma unroll
        for (int rr = 0; rr < 4; ++rr) {
          const int row = rt * 16 + kc * 4 + rr;
          const int sw = (row & 7) << 3;
#pragma unroll
          for (int ct = 0; ct < 16; ++ct) {
            const int j = (wv * 256 + ct * 16 + c16) & 511;
            float r = bf2f(RB[row * 512 + j]);
            float z = bf2f(ZB[row * 512 + j]);
            float hn = bf2f(HB[row * 512 + j]);
            float hin = bf2f(A0[row * 1024 + ((512 + j) ^ sw)]);
            float h1 = (1.f - z) * tanhf(acc[rt][ct][rr] + r * hn) + z * hin;
            A0[row * 1024 + (j ^ sw)] = f2bf(h1);
          }
        }
    }
    __syncthreads();

    // ---- cell1 GEMM: acc = h1(32x512) @ W1-cols, B staged 16-wide ----
#pragma unroll
    for (int rt = 0; rt < 2; ++rt)
#pragma unroll
      for (int ct = 0; ct < 16; ++ct) acc[rt][ct] = (f32x4){0.f, 0.f, 0.f, 0.f};
#pragma unroll 1
    for (int kb = 0; kb < 16; ++kb) {
      const int k = kb * 32 + kc * 8;
      short8 a0 = *(const short8*)&A0[c16 * 1024 + (k ^ sw0)];
      short8 a1 = *(const short8*)&A0[(16 + c16) * 1024 + (k ^ sw0)];
      short8 bq[16];
#pragma unroll
      for (int ct = 0; ct < 16; ++ct)
        bq[ct] = *(const short8*)(W1p + (size_t)((wv * 16 + ct) * 16 + kb) * 512 + lane16);
#pragma unroll
      for (int ct = 0; ct < 16; ++ct) {
        acc[0][ct] = __builtin_amdgcn_mfma_f32_16x16x32_bf16(a0, bq[ct], acc[0][ct], 0, 0, 0);
        acc[1][ct] = __builtin_amdgcn_mfma_f32_16x16x32_bf16(a1, bq[ct], acc[1][ct], 0, 0, 0);
      }
    }
    __syncthreads();

    // ---- cell1: bias + stats ----
#pragma unroll
    for (int ct = 0; ct < 16; ++ct) {
      const int col = wv * 256 + ct * 16 + c16;
      const int j = col & 511;
      float bs = (gate == 3) ? bh_n[512 + j] : bi[1536 + col];
#pragma unroll
      for (int rt = 0; rt < 2; ++rt)
#pragma unroll
        for (int rr = 0; rr < 4; ++rr) acc[rt][ct][rr] += bs;
    }
    if (gate < 2) {
#pragma unroll
      for (int rt = 0; rt < 2; ++rt)
#pragma unroll
        for (int rr = 0; rr < 4; ++rr) {
          float s = 0.f, q = 0.f;
#pragma unroll
          for (int ct = 0; ct < 16; ++ct) { float v = acc[rt][ct][rr]; s += v; q += v * v; }
#pragma unroll
          for (int o = 8; o >= 1; o >>= 1) { s += __shfl_xor(s, o); q += __shfl_xor(q, o); }
          if (c16 == 0) {
            const int row = rt * 16 + kc * 4 + rr;
            st1[gate * 128 + row * 4 + half * 2 + 0] = s;
            st1[gate * 128 + row * 4 + half * 2 + 1] = q;
          }
        }
    }
    __syncthreads();

    // ---- cell1 gates ----
    if (gate < 2) {
#pragma unroll
      for (int rt = 0; rt < 2; ++rt)
#pragma unroll
        for (int rr = 0; rr < 4; ++rr) {
          const int row = rt * 16 + kc * 4 + rr;
          float S = st1[gate * 128 + row * 4 + 0] + st1[gate * 128 + row * 4 + 2];
          float Q = st1[gate * 128 + row * 4 + 1] + st1[gate * 128 + row * 4 + 3];
          float m = S * (1.f / 512.f);
          float vv = Q * (1.f / 512.f) - m * m;
          float ir = rsqrtf(vv + 1e-6f);
#pragma unroll
          for (int ct = 0; ct < 16; ++ct) {
            const int col = wv * 256 + ct * 16 + c16;
            const int j = col & 511;
            float gv = sigf((acc[rt][ct][rr] - m) * ir * ln_s[1024 + gate * 512 + j] +
                            ln_b[1024 + gate * 512 + j]);
            ((gate == 0) ? RB : ZB)[row * 512 + j] = f2bf(gv);
          }
        }
    } else if (gate == 3) {
#pragma unroll
      for (int rt = 0; rt < 2; ++rt)
#pragma unroll
        for (int rr = 0; rr < 4; ++rr) {
          const int row = rt * 16 + kc * 4 + rr;
#pragma unroll
          for (int ct = 0; ct < 16; ++ct) {
            const int j = (wv * 256 + ct * 16 + c16) & 511;
            HB[row * 512 + j] = f2bf(acc[rt][ct][rr]);
          }
        }
    }
    __syncthreads();

    // ---- cell1 combine -> ys[t,b] (+out at t=511) ----
    if (gate == 2) {
#pragma unroll
      for (int rt = 0; rt < 2; ++rt)
#pragma unroll
        for (int rr = 0; rr < 4; ++rr) {
          const int row = rt * 16 + kc * 4 + rr;
          const int sw = (row & 7) << 3;
          const u32 m = g * 32 + (u32)row;
          if (m >= M) continue;
          const u32 e = bucket[gb + row];
          const int t = (int)((e >> 7) & 511), b = (int)(e & 127);
          float* yrow = ys + (size_t)t * (BB * HH) + (size_t)b * HH;
#pragma unroll
          for (int ct = 0; ct < 16; ++ct) {
            const int j = (wv * 256 + ct * 16 + c16) & 511;
            float r = bf2f(RB[row * 512 + j]);
            float z = bf2f(ZB[row * 512 + j]);
            float hn = bf2f(HB[row * 512 + j]);
            float h1v = bf2f(A0[row * 1024 + (j ^ sw)]);
            float h2 = (1.f - z) * tanhf(acc[rt][ct][rr] + r * hn) + z * h1v;
            yrow[j] = h2;
            if (t == TT - 1) out[(size_t)b * HH + j] = h2;
          }
        }
    }
    __syncthreads();
  }
}

// ---------------- cleanup: cells with d >= RCAP (normally zero) ----------------
__global__ __launch_bounds__(256, 1) void cleanup_kernel(
    const float* __restrict__ ins, const void* __restrict__ resets,
    const unsigned* __restrict__ cnt, const float* __restrict__ bi,
    const float* __restrict__ bh_n, const float* __restrict__ ln_s,
    const float* __restrict__ ln_b, const short* __restrict__ W0p,
    const short* __restrict__ W1p, float* __restrict__ out) {
  __shared__ float pre[2048];
  __shared__ float hbuf[512];
  __shared__ float red[4][4];
  const int b = blockIdx.x, tid = threadIdx.x;
  const int wv = tid >> 6, l = tid & 63;
  const int rmode = (int)cnt[FLAG_WORD];
  float* ys = out + BB * HH;
  int d = 0;
  for (int t = 0; t < TT; ++t) {
    bool rs = rmode ? (((const int*)resets)[t * BB + b] != 0)
                    : (((const unsigned char*)resets)[t * BB + b] != 0);
    d = (t == 0 || rs) ? 0 : d + 1;
    if (d < RCAP) continue;
    const float* hin = ys + (size_t)(t - 1) * (BB * HH) + (size_t)b * HH;
    const float* insr = ins + (size_t)t * (BB * HH) + (size_t)b * HH;
    for (int c = tid; c < 2048; c += 256) {
      float s = 0.f;
      for (int k = 0; k < 512; ++k) s += insr[k] * bf2f(W0p[w0idx(c, k)]);
      for (int k = 0; k < 512; ++k) s += hin[k] * bf2f(W0p[w0idx(c, 512 + k)]);
      pre[c] = s;
    }
    __syncthreads();
    float s0 = 0, q0 = 0, s1 = 0, q1 = 0;
    for (int j = tid; j < 512; j += 256) {
      float a = pre[j] + bi[j]; s0 += a; q0 += a * a;
      float c2 = pre[512 + j] + bi[512 + j]; s1 += c2; q1 += c2 * c2;
    }
#pragma unroll
    for (int o = 32; o >= 1; o >>= 1) {
      s0 += __shfl_xor(s0, o); q0 += __shfl_xor(q0, o);
      s1 += __shfl_xor(s1, o); q1 += __shfl_xor(q1, o);
    }
    if (l == 0) { red[wv][0] = s0; red[wv][1] = q0; red[wv][2] = s1; red[wv][3] = q1; }
    __syncthreads();
    float S0 = red[0][0] + red[1][0] + red[2][0] + red[3][0];
    float Q0 = red[0][1] + red[1][1] + red[2][1] + red[3][1];
    float S1 = red[0][2] + red[1][2] + red[2][2] + red[3][2];
    float Q1 = red[0][3] + red[1][3] + red[2][3] + red[3][3];
    float mr = S0 / 512.f, vr = Q0 / 512.f - mr * mr, ir = rsqrtf(vr + 1e-6f);
    float mz = S1 / 512.f, vz = Q1 / 512.f - mz * mz, iz = rsqrtf(vz + 1e-6f);
    __syncthreads();
    for (int j = tid; j < 512; j += 256) {
      float rg = sigf((pre[j] + bi[j] - mr) * ir * ln_s[j] + ln_b[j]);
      float zg = sigf((pre[512 + j] + bi[512 + j] - mz) * iz * ln_s[512 + j] + ln_b[512 + j]);
      float nn = tanhf(pre[1024 + j] + bi[1024 + j] + rg * (pre[1536 + j] + bh_n[j]));
      hbuf[j] = (1.f - zg) * nn + zg * hin[j];
    }
    __syncthreads();
    for (int c = tid; c < 2048; c += 256) {
      float s = 0.f;
      for (int k = 0; k < 512; ++k) s += hbuf[k] * bf2f(W1p[w1idx(c, k)]);
      pre[c] = s;
    }
    __syncthreads();
    s0 = 0; q0 = 0; s1 = 0; q1 = 0;
    for (int j = tid; j < 512; j += 256) {
      float a = pre[j] + bi[1536 + j]; s0 += a; q0 += a * a;
      float c2 = pre[512 + j] + bi[2048 + j]; s1 += c2; q1 += c2 * c2;
    }
#pragma unroll
    for (int o = 32; o >= 1; o >>= 1) {
      s0 += __shfl_xor(s0, o); q0 += __shfl_xor(q0, o);
      s1 += __shfl_xor(s1, o); q1 += __shfl_xor(q1, o);
    }
    if (l == 0) { red[wv][0] = s0; red[wv][1] = q0; red[wv][2] = s1; red[wv][3] = q1; }
    __syncthreads();
    S0 = red[0][0] + red[1][0] + red[2][0] + red[3][0];
    Q0 = red[0][1] + red[1][1] + red[2][1] + red[3][1];
    S1 = red[0][2] + red[1][2] + red[2][2] + red[3][2];
    Q1 = red[0][3] + red[1][3] + red[2][3] + red[3][3];
    mr = S0 / 512.f; vr = Q0 / 512.f - mr * mr; ir = rsqrtf(vr + 1e-6f);
    mz = S1 / 512.f; vz = Q1 / 512.f - mz * mz; iz = rsqrtf(vz + 1e-6f);
    __syncthreads();
    for (int j = tid; j < 512; j += 256) {
      float rg = sigf((pre[j] + bi[1536 + j] - mr) * ir * ln_s[1024 + j] + ln_b[1024 + j]);
      float zg = sigf((pre[512 + j] + bi[2048 + j] - mz) * iz * ln_s[1536 + j] + ln_b[1536 + j]);
      float nn = tanhf(pre[1024 + j] + bi[2560 + j] + rg * (pre[1536 + j] + bh_n[512 + j]));
      float h2 = (1.f - zg) * nn + zg * hbuf[j];
      ys[(size_t)t * (BB * HH) + (size_t)b * HH + j] = h2;
      if (t == TT - 1) out[(size_t)b * HH + j] = h2;
    }
    __syncthreads();
  }
}

extern "C" void kernel_launch(void* const* d_in, const int* in_sizes, int n_in,
                              void* d_out, int out_size, void* d_ws, size_t ws_size,
                              hipStream_t stream) {
  const float* ins   = (const float*)d_in[0];
  const void*  rstp  = d_in[1];
  const float* h0    = (const float*)d_in[2];
  const float* Wi    = (const float*)d_in[3];
  const float* bi    = (const float*)d_in[4];
  const float* Wh_rz = (const float*)d_in[5];
  const float* Wh_n  = (const float*)d_in[6];
  const float* bh_n  = (const float*)d_in[7];
  const float* ln_s  = (const float*)d_in[8];
  const float* ln_b  = (const float*)d_in[9];
  (void)in_sizes; (void)n_in; (void)out_size; (void)ws_size;

  char* ws = (char*)d_ws;
  unsigned* cnt = (unsigned*)ws;                       // off[0..RCAP] + flag @32768
  size_t off = 144 * 1024;
  u32*   bucket = (u32*)(ws + off);  off += (size_t)TT * BB * 4;       // 256 KB
  short* W0p    = (short*)(ws + off); off += (size_t)2048 * 1024 * 2;  // 4 MB
  short* W1p    = (short*)(ws + off); off += (size_t)2048 * 512 * 2;   // 2 MB
  // total ws use ~6.5 MB

  hipMemsetAsync(cnt, 0, (FLAG_WORD + 1) * sizeof(unsigned), stream);
  pack_kernel<<<1536, 256, 0, stream>>>(Wi, Wh_rz, Wh_n, rstp, W0p, W1p, cnt);
  prep_kernel<<<1, 128, 0, stream>>>(rstp, cnt, bucket);
  float* outp = (float*)d_out;
  for (int tau = 0; tau < RCAP; ++tau) {
    round_kernel<<<256, 512, 0, stream>>>(tau, ins, rstp, h0, bi, bh_n, ln_s, ln_b,
                                          W0p, W1p, cnt, bucket, outp);
  }
  cleanup_kernel<<<BB, 256, 0, stream>>>(ins, rstp, cnt, bi, bh_n, ln_s, ln_b,
                                         W0p, W1p, outp);
}